// Round 1
// baseline (1007.476 us; speedup 1.0000x reference)
//
#include <hip/hip_runtime.h>
#include <hip/hip_bf16.h>

typedef __bf16 bf16_t;
typedef __attribute__((ext_vector_type(8))) __bf16 bf16x8;
typedef __attribute__((ext_vector_type(4))) float f32x4;

// ---------------- Phase A: h = relu(bn(x @ w_pre + b_pre)) ----------------
// K1: compute y tile in regs, accumulate per-column sum/sumsq (no y store).
__global__ __launch_bounds__(256) void k_pre_stats(const float* __restrict__ x,
        const float* __restrict__ w_pre, const float* __restrict__ b_pre,
        float* __restrict__ stats) {
    __shared__ float ws[64][128];
    __shared__ float xs[16][64];
    int tid = threadIdx.x;
    for (int i = tid; i < 64 * 128; i += 256) ws[i >> 7][i & 127] = w_pre[i];
    int row0 = blockIdx.x * 16;
    for (int i = tid; i < 16 * 64; i += 256) xs[i >> 6][i & 63] = x[row0 * 64 + i];
    __syncthreads();
    int col = tid & 127, rg = tid >> 7;
    float acc[8] = {};
    for (int k = 0; k < 64; ++k) {
        float wv = ws[k][col];
#pragma unroll
        for (int i = 0; i < 8; ++i) acc[i] += xs[rg * 8 + i][k] * wv;
    }
    float b = b_pre[col], s1 = 0.f, s2 = 0.f;
#pragma unroll
    for (int i = 0; i < 8; ++i) { float y = acc[i] + b; s1 += y; s2 += y * y; }
    atomicAdd(&stats[col], s1);
    atomicAdd(&stats[128 + col], s2);
}

// K2: fold bias+BN into per-column scale/shift: h = A*ynb + B
__global__ void k_pre_finalize(const float* __restrict__ stats, const float* __restrict__ b_pre,
                               const float* __restrict__ g_pre, const float* __restrict__ be_pre,
                               float* __restrict__ ab, float invN) {
    int c = threadIdx.x;
    float mu = stats[c] * invN;
    float var = stats[128 + c] * invN - mu * mu;
    float a = g_pre[c] * rsqrtf(var + 1e-3f);
    ab[c] = a;
    ab[128 + c] = a * (b_pre[c] - mu) + be_pre[c];
}

// K3: recompute GEMM, apply scale/shift+relu, write h as bf16 (contiguous 16B stores)
__global__ __launch_bounds__(256) void k_pre_apply(const float* __restrict__ x,
        const float* __restrict__ w_pre, const float* __restrict__ ab,
        bf16_t* __restrict__ h) {
    __shared__ float ws[64][128];
    __shared__ float xs[16][64];
    int tid = threadIdx.x;
    for (int i = tid; i < 64 * 128; i += 256) ws[i >> 7][i & 127] = w_pre[i];
    int row0 = blockIdx.x * 16;
    for (int i = tid; i < 16 * 64; i += 256) xs[i >> 6][i & 63] = x[row0 * 64 + i];
    __syncthreads();
    int r = tid >> 4, c0 = (tid & 15) * 8;
    float acc[8] = {};
    for (int k = 0; k < 64; ++k) {
        float xv = xs[r][k];
#pragma unroll
        for (int j = 0; j < 8; ++j) acc[j] += xv * ws[k][c0 + j];
    }
    bf16x8 out;
#pragma unroll
    for (int j = 0; j < 8; ++j) {
        float v = ab[c0 + j] * acc[j] + ab[128 + c0 + j];
        out[j] = (bf16_t)fmaxf(v, 0.f);
    }
    *(bf16x8*)(h + (row0 + r) * 128 + c0) = out;
}

// ---------------- Phase B: EdgeConv fused with both segment sums ----------------
// msg = relu([h_i | h_j - h_i] @ w_cn + b_cn); p[seg[src]] += msg  (atomics)
// 256 threads = 4 waves; wave w owns cols [32w, 32w+32); B-frags in registers.
// LDS A tile: 64 edges x 256 bf16, row stride 264 (528B) to break bank conflicts.
__global__ __launch_bounds__(256, 2) void k_edge(const bf16_t* __restrict__ h,
        const int* __restrict__ src, const int* __restrict__ dst,
        const int* __restrict__ seg, const float* __restrict__ w_cn,
        const float* __restrict__ b_cn, float* __restrict__ p, int E) {
    __shared__ bf16_t a_tile[64 * 264];
    __shared__ int g_lds[64];
    const int tid = threadIdx.x;
    const int lane = tid & 63;
    const int wv = tid >> 6;
    const int n0 = wv * 32;
    const int l16 = lane & 15;
    const int lg = lane >> 4;

    // B fragments: B[k][n], n = n0+16c+l16, k = 32s + 8*lg + j
    bf16x8 bfr[8][2];
    float bias0 = b_cn[n0 + l16], bias1 = b_cn[n0 + 16 + l16];
#pragma unroll
    for (int s = 0; s < 8; ++s) {
#pragma unroll
        for (int c = 0; c < 2; ++c) {
            bf16x8 t;
#pragma unroll
            for (int j = 0; j < 8; ++j) {
                int k = 32 * s + 8 * lg + j;
                t[j] = (bf16_t)w_cn[k * 128 + n0 + 16 * c + l16];
            }
            bfr[s][c] = t;
        }
    }

    const int ntiles = (E + 63) >> 6;
    const int r = tid >> 2, u = tid & 3;  // 4 threads per edge row
    for (int t = blockIdx.x; t < ntiles; t += gridDim.x) {
        int e = t * 64 + r;
        int ec = e < E ? e : E - 1;
        int si = src[ec], di = dst[ec];
        if (u == 0) g_lds[r] = seg[si];
        const bf16_t* hi = h + si * 128 + u * 32;
        const bf16_t* hj = h + di * 128 + u * 32;
        bf16_t* rowp = a_tile + r * 264;
#pragma unroll
        for (int c4 = 0; c4 < 4; ++c4) {
            bf16x8 hv = *(const bf16x8*)(hi + c4 * 8);
            bf16x8 jv = *(const bf16x8*)(hj + c4 * 8);
            bf16x8 dv;
#pragma unroll
            for (int j = 0; j < 8; ++j) dv[j] = (bf16_t)((float)jv[j] - (float)hv[j]);
            *(bf16x8*)(rowp + u * 32 + c4 * 8) = hv;
            *(bf16x8*)(rowp + 128 + u * 32 + c4 * 8) = dv;
        }
        __syncthreads();

        f32x4 acc[4][2];
#pragma unroll
        for (int rt = 0; rt < 4; ++rt) {
            acc[rt][0] = (f32x4){bias0, bias0, bias0, bias0};
            acc[rt][1] = (f32x4){bias1, bias1, bias1, bias1};
        }
#pragma unroll
        for (int s = 0; s < 8; ++s) {
            int kb = s * 32 + lg * 8;  // bf16 element index in row
            bf16x8 afr[4];
#pragma unroll
            for (int rt = 0; rt < 4; ++rt)
                afr[rt] = *(const bf16x8*)(a_tile + (rt * 16 + l16) * 264 + kb);
#pragma unroll
            for (int rt = 0; rt < 4; ++rt) {
                acc[rt][0] = __builtin_amdgcn_mfma_f32_16x16x32_bf16(afr[rt], bfr[s][0], acc[rt][0], 0, 0, 0);
                acc[rt][1] = __builtin_amdgcn_mfma_f32_16x16x32_bf16(afr[rt], bfr[s][1], acc[rt][1], 0, 0, 0);
            }
        }

        // epilogue: relu + fused double-segment-sum via atomics into p[512][128]
#pragma unroll
        for (int rt = 0; rt < 4; ++rt) {
            int rbase = rt * 16 + lg * 4;
#pragma unroll
            for (int reg = 0; reg < 4; ++reg) {
                int row = rbase + reg;
                int eg = t * 64 + row;
                if (eg < E) {
                    int g = g_lds[row];
                    float v0 = acc[rt][0][reg];
                    float v1 = acc[rt][1][reg];
                    if (v0 > 0.f) atomicAdd(&p[g * 128 + n0 + l16], v0);
                    if (v1 > 0.f) atomicAdd(&p[g * 128 + n0 + 16 + l16], v1);
                }
            }
        }
        __syncthreads();
    }
}

// ---------------- Phase C: post MLP + BN + head ----------------
__global__ __launch_bounds__(256) void k_post_gemm(const float* __restrict__ p,
        const float* __restrict__ w_post, const float* __restrict__ b_post,
        float* __restrict__ y, float* __restrict__ stats) {
    int tid = threadIdx.x;
    int row0 = blockIdx.x * 16;
    int col = tid & 127, rg = tid >> 7;
    float acc[8] = {};
    for (int k = 0; k < 128; ++k) {
        float wv = w_post[k * 128 + col];
#pragma unroll
        for (int i = 0; i < 8; ++i) acc[i] += p[(row0 + rg * 8 + i) * 128 + k] * wv;
    }
    float b = b_post[col], s1 = 0.f, s2 = 0.f;
#pragma unroll
    for (int i = 0; i < 8; ++i) {
        float yv = acc[i] + b;
        y[(row0 + rg * 8 + i) * 128 + col] = yv;
        s1 += yv; s2 += yv * yv;
    }
    atomicAdd(&stats[col], s1);
    atomicAdd(&stats[128 + col], s2);
}

__global__ void k_post_finalize(const float* __restrict__ stats, const float* __restrict__ g_post,
                                const float* __restrict__ be_post, float* __restrict__ ab, float invG) {
    int c = threadIdx.x;
    float mu = stats[c] * invG;
    float var = stats[128 + c] * invG - mu * mu;
    float a = g_post[c] * rsqrtf(var + 1e-3f);
    ab[c] = a;
    ab[128 + c] = be_post[c] - mu * a;
}

__global__ __launch_bounds__(256) void k_out(const float* __restrict__ y,
        const float* __restrict__ ab, const float* __restrict__ w_out,
        const float* __restrict__ b_out, float* __restrict__ out) {
    int lane = threadIdx.x & 63;
    int wv = threadIdx.x >> 6;
    int row = blockIdx.x * 4 + wv;
    int c0 = lane * 2;
    float v = 0.f;
#pragma unroll
    for (int j = 0; j < 2; ++j) {
        int c = c0 + j;
        float t = fmaxf(ab[c] * y[row * 128 + c] + ab[128 + c], 0.f);
        v += t * w_out[c];
    }
#pragma unroll
    for (int m = 32; m >= 1; m >>= 1) v += __shfl_xor(v, m, 64);
    if (lane == 0) out[row] = 1.f / (1.f + expf(-(v + b_out[0])));
}

extern "C" void kernel_launch(void* const* d_in, const int* in_sizes, int n_in,
                              void* d_out, int out_size, void* d_ws, size_t ws_size,
                              hipStream_t stream) {
    const float* x      = (const float*)d_in[0];
    const int*   src    = (const int*)d_in[1];
    const int*   dst    = (const int*)d_in[2];
    const int*   seg    = (const int*)d_in[3];
    const float* w_pre  = (const float*)d_in[4];
    const float* b_pre  = (const float*)d_in[5];
    const float* g_pre  = (const float*)d_in[6];
    const float* be_pre = (const float*)d_in[7];
    const float* w_cn   = (const float*)d_in[8];
    const float* b_cn   = (const float*)d_in[9];
    const float* w_post = (const float*)d_in[10];
    const float* b_post = (const float*)d_in[11];
    const float* g_post = (const float*)d_in[12];
    const float* be_post= (const float*)d_in[13];
    const float* w_out  = (const float*)d_in[14];
    const float* b_out  = (const float*)d_in[15];
    const int E = in_sizes[1];
    const int N = in_sizes[3];

    char* ws = (char*)d_ws;
    float*  stats_pre  = (float*)(ws + 0);                       // 256 f32
    float*  ab_pre     = (float*)(ws + 1024);                    // 256 f32
    float*  stats_post = (float*)(ws + 2048);                    // 256 f32
    float*  ab_post    = (float*)(ws + 3072);                    // 256 f32
    float*  pbuf       = (float*)(ws + 4096);                    // 512*128 f32
    float*  ybuf       = (float*)(ws + 4096 + 512 * 128 * 4);    // 512*128 f32
    bf16_t* hbuf       = (bf16_t*)(ws + 4096 + 2 * 512 * 128 * 4); // N*128 bf16

    // zero stats + p accumulator (ws is poisoned before every call)
    hipMemsetAsync(d_ws, 0, 4096 + 512 * 128 * 4, stream);

    int nb_pre = N / 16;  // 3125
    k_pre_stats<<<nb_pre, 256, 0, stream>>>(x, w_pre, b_pre, stats_pre);
    k_pre_finalize<<<1, 128, 0, stream>>>(stats_pre, b_pre, g_pre, be_pre, ab_pre, 1.f / (float)N);
    k_pre_apply<<<nb_pre, 256, 0, stream>>>(x, w_pre, ab_pre, hbuf);
    k_edge<<<1024, 256, 0, stream>>>(hbuf, src, dst, seg, w_cn, b_cn, pbuf, E);
    k_post_gemm<<<32, 256, 0, stream>>>(pbuf, w_post, b_post, ybuf, stats_post);
    k_post_finalize<<<1, 128, 0, stream>>>(stats_post, g_post, be_post, ab_post, 1.f / 512.f);
    k_out<<<128, 256, 0, stream>>>(ybuf, ab_post, w_out, b_out, (float*)d_out);
}

// Round 4
// 568.502 us; speedup vs baseline: 1.7722x; 1.7722x over previous
//
#include <hip/hip_runtime.h>
#include <hip/hip_bf16.h>

typedef __bf16 bf16_t;
typedef _Float16 f16_t;
typedef __attribute__((ext_vector_type(8))) __bf16 bf16x8;
typedef __attribute__((ext_vector_type(8))) _Float16 f16x8;
typedef __attribute__((ext_vector_type(4))) float f32x4;

// ---------------- Phase A: h = relu(bn(x @ w_pre + b_pre)) ----------------
__global__ __launch_bounds__(256) void k_pre_stats(const float* __restrict__ x,
        const float* __restrict__ w_pre, const float* __restrict__ b_pre,
        float* __restrict__ stats) {
    __shared__ float ws[64][128];
    __shared__ float xs[16][64];
    int tid = threadIdx.x;
    for (int i = tid; i < 64 * 128; i += 256) ws[i >> 7][i & 127] = w_pre[i];
    int row0 = blockIdx.x * 16;
    for (int i = tid; i < 16 * 64; i += 256) xs[i >> 6][i & 63] = x[row0 * 64 + i];
    __syncthreads();
    int col = tid & 127, rg = tid >> 7;
    float acc[8] = {};
    for (int k = 0; k < 64; ++k) {
        float wv = ws[k][col];
#pragma unroll
        for (int i = 0; i < 8; ++i) acc[i] += xs[rg * 8 + i][k] * wv;
    }
    float b = b_pre[col], s1 = 0.f, s2 = 0.f;
#pragma unroll
    for (int i = 0; i < 8; ++i) { float y = acc[i] + b; s1 += y; s2 += y * y; }
    atomicAdd(&stats[col], s1);
    atomicAdd(&stats[128 + col], s2);
}

__global__ void k_pre_finalize(const float* __restrict__ stats, const float* __restrict__ b_pre,
                               const float* __restrict__ g_pre, const float* __restrict__ be_pre,
                               float* __restrict__ ab, float invN) {
    int c = threadIdx.x;
    float mu = stats[c] * invN;
    float var = stats[128 + c] * invN - mu * mu;
    float a = g_pre[c] * rsqrtf(var + 1e-3f);
    ab[c] = a;
    ab[128 + c] = a * (b_pre[c] - mu) + be_pre[c];
}

__global__ __launch_bounds__(256) void k_pre_apply(const float* __restrict__ x,
        const float* __restrict__ w_pre, const float* __restrict__ ab,
        bf16_t* __restrict__ h) {
    __shared__ float ws[64][128];
    __shared__ float xs[16][64];
    int tid = threadIdx.x;
    for (int i = tid; i < 64 * 128; i += 256) ws[i >> 7][i & 127] = w_pre[i];
    int row0 = blockIdx.x * 16;
    for (int i = tid; i < 16 * 64; i += 256) xs[i >> 6][i & 63] = x[row0 * 64 + i];
    __syncthreads();
    int r = tid >> 4, c0 = (tid & 15) * 8;
    float acc[8] = {};
    for (int k = 0; k < 64; ++k) {
        float xv = xs[r][k];
#pragma unroll
        for (int j = 0; j < 8; ++j) acc[j] += xv * ws[k][c0 + j];
    }
    bf16x8 out;
#pragma unroll
    for (int j = 0; j < 8; ++j) {
        float v = ab[c0 + j] * acc[j] + ab[128 + c0 + j];
        out[j] = (bf16_t)fmaxf(v, 0.f);
    }
    *(bf16x8*)(h + (row0 + r) * 128 + c0) = out;
}

// ---------------- W' = [w1 - w2 | w2] as bf16 [128][256] ----------------
__global__ __launch_bounds__(256) void k_wprime(const float* __restrict__ w_cn,
        bf16_t* __restrict__ wp) {
    int k = blockIdx.x;           // 0..127
    int c = threadIdx.x & 127, half = threadIdx.x >> 7;
    if (half == 0)
        wp[k * 256 + c] = (bf16_t)(w_cn[k * 128 + c] - w_cn[(128 + k) * 128 + c]);
    else
        wp[k * 256 + 128 + c] = (bf16_t)(w_cn[(128 + k) * 128 + c]);
}

// ---------------- k_uv: [u|v] = h @ W' (+b_cn on u half), fp16 out ----------------
// Block: 64 rows x 256 cols, 4 waves (wave -> 64-col slab). K=128 in one LDS stage.
__global__ __launch_bounds__(256) void k_uv(const bf16_t* __restrict__ h,
        const bf16_t* __restrict__ wp, const float* __restrict__ b_cn,
        f16_t* __restrict__ u, f16_t* __restrict__ v, int N) {
    __shared__ char smem[64 * 264 * 2];
    bf16_t* at = (bf16_t*)smem;   // A tile, row stride 136 elements
    f16_t* ot = (f16_t*)smem;     // output staging, row stride 264 elements

    const int tid = threadIdx.x;
    const int lane = tid & 63;
    const int wv = tid >> 6;
    const int n0 = wv * 64;
    const int l16 = lane & 15;
    const int lg = lane >> 4;
    const int row0 = blockIdx.x * 64;

    // stage A: 64 rows x 128 bf16 (clamped rows for tail block)
    {
        int r = tid >> 2, q = tid & 3;
        int rg = row0 + r; if (rg >= N) rg = N - 1;
        const bf16_t* hr = h + (size_t)rg * 128 + q * 32;
        bf16_t* dr = at + r * 136 + q * 32;
#pragma unroll
        for (int c4 = 0; c4 < 4; ++c4)
            *(bf16x8*)(dr + c4 * 8) = *(const bf16x8*)(hr + c4 * 8);
    }

    // B fragments from global: k = 32s+8lg+j, col n = n0+16c+l16
    bf16x8 bfr[4][4];
#pragma unroll
    for (int s = 0; s < 4; ++s)
#pragma unroll
        for (int c = 0; c < 4; ++c) {
            bf16x8 t;
#pragma unroll
            for (int j = 0; j < 8; ++j)
                t[j] = wp[(32 * s + 8 * lg + j) * 256 + n0 + 16 * c + l16];
            bfr[s][c] = t;
        }

    f32x4 acc[4][4];
#pragma unroll
    for (int c = 0; c < 4; ++c) {
        int n = n0 + 16 * c + l16;
        float bias = (n < 128) ? b_cn[n] : 0.f;
        f32x4 ini = {bias, bias, bias, bias};
#pragma unroll
        for (int rt = 0; rt < 4; ++rt) acc[rt][c] = ini;
    }
    __syncthreads();

#pragma unroll
    for (int s = 0; s < 4; ++s) {
        bf16x8 afr[4];
#pragma unroll
        for (int rt = 0; rt < 4; ++rt)
            afr[rt] = *(const bf16x8*)(at + (rt * 16 + l16) * 136 + 32 * s + 8 * lg);
#pragma unroll
        for (int rt = 0; rt < 4; ++rt)
#pragma unroll
            for (int c = 0; c < 4; ++c)
                acc[rt][c] = __builtin_amdgcn_mfma_f32_16x16x32_bf16(afr[rt], bfr[s][c], acc[rt][c], 0, 0, 0);
    }
    __syncthreads();  // A tile dead; reuse smem for output staging

    // epilogue: regs -> LDS (f16), C/D layout col=lane&15, row=lg*4+reg
#pragma unroll
    for (int rt = 0; rt < 4; ++rt)
#pragma unroll
        for (int c = 0; c < 4; ++c) {
            int n = n0 + 16 * c + l16;
#pragma unroll
            for (int reg = 0; reg < 4; ++reg) {
                int r = rt * 16 + lg * 4 + reg;
                ot[r * 264 + n] = (f16_t)acc[rt][c][reg];
            }
        }
    __syncthreads();

    // coalesced copy out: wave handles rows wv*16..wv*16+15, 2 rows per iter
#pragma unroll
    for (int it = 0; it < 8; ++it) {
        int r = wv * 16 + it * 2 + (lane >> 5);
        int cc = (lane & 31) * 8;
        int rg = row0 + r;
        if (rg < N) {
            f16x8 w8 = *(const f16x8*)(ot + r * 264 + cc);
            if (cc < 128) *(f16x8*)(u + (size_t)rg * 128 + cc) = w8;
            else          *(f16x8*)(v + (size_t)rg * 128 + cc - 128) = w8;
        }
    }
}

// ---------------- counting sort of edges by g = seg[src[e]] ----------------
__global__ __launch_bounds__(256) void k_hist(const int* __restrict__ src,
        const int* __restrict__ seg, int* __restrict__ gcnt, int E) {
    __shared__ int lh[512];
    int tid = threadIdx.x;
    for (int i = tid; i < 512; i += 256) lh[i] = 0;
    __syncthreads();
    for (int e = blockIdx.x * 256 + tid; e < E; e += gridDim.x * 256)
        atomicAdd(&lh[seg[src[e]]], 1);
    __syncthreads();
    for (int i = tid; i < 512; i += 256)
        if (lh[i]) atomicAdd(&gcnt[i], lh[i]);
}

__global__ __launch_bounds__(512) void k_scan(const int* __restrict__ gcnt,
        int* __restrict__ offs, int* __restrict__ cursor) {
    __shared__ int s[512];
    int tid = threadIdx.x;
    s[tid] = gcnt[tid];
    __syncthreads();
    for (int off = 1; off < 512; off <<= 1) {
        int v = (tid >= off) ? s[tid - off] : 0;
        __syncthreads();
        s[tid] += v;
        __syncthreads();
    }
    offs[tid + 1] = s[tid];
    int ex = tid ? s[tid - 1] : 0;
    if (tid == 0) offs[0] = 0;
    cursor[tid] = ex;
}

__global__ __launch_bounds__(256) void k_scatter(const int* __restrict__ src,
        const int* __restrict__ dst, const int* __restrict__ seg,
        int* __restrict__ cursor, int2* __restrict__ sorted, int E, int CH) {
    __shared__ int lh[512];
    __shared__ int lbase[512];
    int tid = threadIdx.x;
    int e0 = blockIdx.x * CH;
    int e1 = min(E, e0 + CH);
    for (int i = tid; i < 512; i += 256) lh[i] = 0;
    __syncthreads();
    for (int e = e0 + tid; e < e1; e += 256)
        atomicAdd(&lh[seg[src[e]]], 1);
    __syncthreads();
    for (int i = tid; i < 512; i += 256) {
        int c = lh[i];
        lbase[i] = c ? atomicAdd(&cursor[i], c) : 0;
        lh[i] = 0;
    }
    __syncthreads();
    for (int e = e0 + tid; e < e1; e += 256) {
        int si = src[e];
        int g = seg[si];
        int k = atomicAdd(&lh[g], 1);
        sorted[lbase[g] + k] = make_int2(si, dst[e]);
    }
}

// ---------------- k_agg: p[g] = sum over g's edges of relu(u[src]+v[dst]) ----------------
// One block per graph. Wave processes 4 edges/iter (16 lanes x 8 cols each). No atomics.
__global__ __launch_bounds__(256) void k_agg(const int2* __restrict__ sorted,
        const int* __restrict__ offs, const f16_t* __restrict__ u,
        const f16_t* __restrict__ v, float* __restrict__ p) {
    const int g = blockIdx.x;
    const int s = offs[g], t = offs[g + 1];
    const int tid = threadIdx.x;
    const int lane = tid & 63;
    const int wv = tid >> 6;
    const int sub = lane >> 4;
    const int c0 = (lane & 15) * 8;
    float acc[8] = {};
    for (int base = s + wv * 4; base < t; base += 16) {
        int e = base + sub;
        if (e < t) {
            int2 pr = sorted[e];
            f16x8 uu = *(const f16x8*)(u + (size_t)pr.x * 128 + c0);
            f16x8 vv = *(const f16x8*)(v + (size_t)pr.y * 128 + c0);
#pragma unroll
            for (int j = 0; j < 8; ++j)
                acc[j] += fmaxf((float)uu[j] + (float)vv[j], 0.f);
        }
    }
#pragma unroll
    for (int j = 0; j < 8; ++j) {
        acc[j] += __shfl_xor(acc[j], 16, 64);
        acc[j] += __shfl_xor(acc[j], 32, 64);
    }
    __shared__ float red[4][128];
    if (lane < 16) {
#pragma unroll
        for (int j = 0; j < 8; ++j) red[wv][c0 + j] = acc[j];
    }
    __syncthreads();
    if (tid < 128)
        p[g * 128 + tid] = red[0][tid] + red[1][tid] + red[2][tid] + red[3][tid];
}

// ---------------- Phase C: post MLP + BN + head ----------------
__global__ __launch_bounds__(256) void k_post_gemm(const float* __restrict__ p,
        const float* __restrict__ w_post, const float* __restrict__ b_post,
        float* __restrict__ y, float* __restrict__ stats) {
    int tid = threadIdx.x;
    int row0 = blockIdx.x * 16;
    int col = tid & 127, rg = tid >> 7;
    float acc[8] = {};
    for (int k = 0; k < 128; ++k) {
        float wv = w_post[k * 128 + col];
#pragma unroll
        for (int i = 0; i < 8; ++i) acc[i] += p[(row0 + rg * 8 + i) * 128 + k] * wv;
    }
    float b = b_post[col], s1 = 0.f, s2 = 0.f;
#pragma unroll
    for (int i = 0; i < 8; ++i) {
        float yv = acc[i] + b;
        y[(row0 + rg * 8 + i) * 128 + col] = yv;
        s1 += yv; s2 += yv * yv;
    }
    atomicAdd(&stats[col], s1);
    atomicAdd(&stats[128 + col], s2);
}

__global__ void k_post_finalize(const float* __restrict__ stats, const float* __restrict__ g_post,
                                const float* __restrict__ be_post, float* __restrict__ ab, float invG) {
    int c = threadIdx.x;
    float mu = stats[c] * invG;
    float var = stats[128 + c] * invG - mu * mu;
    float a = g_post[c] * rsqrtf(var + 1e-3f);
    ab[c] = a;
    ab[128 + c] = be_post[c] - mu * a;
}

__global__ __launch_bounds__(256) void k_out(const float* __restrict__ y,
        const float* __restrict__ ab, const float* __restrict__ w_out,
        const float* __restrict__ b_out, float* __restrict__ out) {
    int lane = threadIdx.x & 63;
    int wv = threadIdx.x >> 6;
    int row = blockIdx.x * 4 + wv;
    int c0 = lane * 2;
    float v = 0.f;
#pragma unroll
    for (int j = 0; j < 2; ++j) {
        int c = c0 + j;
        float t = fmaxf(ab[c] * y[row * 128 + c] + ab[128 + c], 0.f);
        v += t * w_out[c];
    }
#pragma unroll
    for (int m = 32; m >= 1; m >>= 1) v += __shfl_xor(v, m, 64);
    if (lane == 0) out[row] = 1.f / (1.f + expf(-(v + b_out[0])));
}

extern "C" void kernel_launch(void* const* d_in, const int* in_sizes, int n_in,
                              void* d_out, int out_size, void* d_ws, size_t ws_size,
                              hipStream_t stream) {
    const float* x      = (const float*)d_in[0];
    const int*   src    = (const int*)d_in[1];
    const int*   dst    = (const int*)d_in[2];
    const int*   seg    = (const int*)d_in[3];
    const float* w_pre  = (const float*)d_in[4];
    const float* b_pre  = (const float*)d_in[5];
    const float* g_pre  = (const float*)d_in[6];
    const float* be_pre = (const float*)d_in[7];
    const float* w_cn   = (const float*)d_in[8];
    const float* b_cn   = (const float*)d_in[9];
    const float* w_post = (const float*)d_in[10];
    const float* b_post = (const float*)d_in[11];
    const float* g_post = (const float*)d_in[12];
    const float* be_post= (const float*)d_in[13];
    const float* w_out  = (const float*)d_in[14];
    const float* b_out  = (const float*)d_in[15];
    const int E = in_sizes[1];
    const int N = in_sizes[3];
    const int G = out_size;

    char* ws = (char*)d_ws;
    float* stats_pre  = (float*)(ws + 0);        // 1KB, zeroed each call
    float* stats_post = (float*)(ws + 1024);     // 1KB, zeroed each call
    int*   gcnt       = (int*)(ws + 2048);       // 2KB, zeroed each call
    float* ab_pre     = (float*)(ws + 4096);
    float* ab_post    = (float*)(ws + 5120);
    int*   offs       = (int*)(ws + 6144);       // 513 ints
    int*   cursor     = (int*)(ws + 10240);      // 512 ints
    bf16_t* wp        = (bf16_t*)(ws + 12288);   // 64KB
    float* pbuf       = (float*)(ws + 131072);   // 256KB
    float* ybuf       = (float*)(ws + 131072 + 262144); // 256KB
    size_t big0 = 1 << 20;
    size_t NB = (((size_t)N * 128 * 2) + 4095) & ~(size_t)4095;   // f16 table bytes
    f16_t* ubuf = (f16_t*)(ws + big0);
    f16_t* vbuf = (f16_t*)(ws + big0 + NB);
    bf16_t* hbuf = (bf16_t*)(ws + big0 + 2 * NB);
    int2* sorted = (int2*)(ws + big0 + 2 * NB);  // aliases hbuf (h dead after k_uv)
    (void)ws_size;

    (void)hipMemsetAsync(d_ws, 0, 4096, stream);

    int nb_pre = (N + 15) / 16;
    k_pre_stats<<<nb_pre, 256, 0, stream>>>(x, w_pre, b_pre, stats_pre);
    k_pre_finalize<<<1, 128, 0, stream>>>(stats_pre, b_pre, g_pre, be_pre, ab_pre, 1.f / (float)N);
    k_pre_apply<<<nb_pre, 256, 0, stream>>>(x, w_pre, ab_pre, hbuf);
    k_wprime<<<128, 256, 0, stream>>>(w_cn, wp);
    k_uv<<<(N + 63) / 64, 256, 0, stream>>>(hbuf, wp, b_cn, ubuf, vbuf, N);
    k_hist<<<512, 256, 0, stream>>>(src, seg, gcnt, E);
    k_scan<<<1, 512, 0, stream>>>(gcnt, offs, cursor);
    int CH = (E + 511) / 512;
    k_scatter<<<512, 256, 0, stream>>>(src, dst, seg, cursor, sorted, E, CH);
    k_agg<<<G, 256, 0, stream>>>(sorted, offs, ubuf, vbuf, pbuf);
    k_post_gemm<<<G / 16, 256, 0, stream>>>(pbuf, w_post, b_post, ybuf, stats_post);
    k_post_finalize<<<1, 128, 0, stream>>>(stats_post, g_post, be_post, ab_post, 1.f / (float)G);
    k_out<<<G / 4, 256, 0, stream>>>(ybuf, ab_post, w_out, b_out, (float*)d_out);
}

// Round 5
// 482.689 us; speedup vs baseline: 2.0872x; 1.1778x over previous
//
#include <hip/hip_runtime.h>
#include <hip/hip_bf16.h>

typedef __bf16 bf16_t;
typedef _Float16 f16_t;
typedef __attribute__((ext_vector_type(8))) __bf16 bf16x8;
typedef __attribute__((ext_vector_type(8))) _Float16 f16x8;
typedef __attribute__((ext_vector_type(4))) float f32x4;

// ---------------- Phase A: h = relu(bn(x @ w_pre + b_pre)) ----------------
__global__ __launch_bounds__(256) void k_pre_stats(const float* __restrict__ x,
        const float* __restrict__ w_pre, const float* __restrict__ b_pre,
        float* __restrict__ stats) {
    __shared__ float ws[64][128];
    __shared__ float xs[16][64];
    int tid = threadIdx.x;
    for (int i = tid; i < 64 * 128; i += 256) ws[i >> 7][i & 127] = w_pre[i];
    int row0 = blockIdx.x * 16;
    for (int i = tid; i < 16 * 64; i += 256) xs[i >> 6][i & 63] = x[row0 * 64 + i];
    __syncthreads();
    int col = tid & 127, rg = tid >> 7;
    float acc[8] = {};
    for (int k = 0; k < 64; ++k) {
        float wv = ws[k][col];
#pragma unroll
        for (int i = 0; i < 8; ++i) acc[i] += xs[rg * 8 + i][k] * wv;
    }
    float b = b_pre[col], s1 = 0.f, s2 = 0.f;
#pragma unroll
    for (int i = 0; i < 8; ++i) { float y = acc[i] + b; s1 += y; s2 += y * y; }
    atomicAdd(&stats[col], s1);
    atomicAdd(&stats[128 + col], s2);
}

__global__ void k_pre_finalize(const float* __restrict__ stats, const float* __restrict__ b_pre,
                               const float* __restrict__ g_pre, const float* __restrict__ be_pre,
                               float* __restrict__ ab, float invN) {
    int c = threadIdx.x;
    float mu = stats[c] * invN;
    float var = stats[128 + c] * invN - mu * mu;
    float a = g_pre[c] * rsqrtf(var + 1e-3f);
    ab[c] = a;
    ab[128 + c] = a * (b_pre[c] - mu) + be_pre[c];
}

__global__ __launch_bounds__(256) void k_pre_apply(const float* __restrict__ x,
        const float* __restrict__ w_pre, const float* __restrict__ ab,
        bf16_t* __restrict__ h) {
    __shared__ float ws[64][128];
    __shared__ float xs[16][64];
    int tid = threadIdx.x;
    for (int i = tid; i < 64 * 128; i += 256) ws[i >> 7][i & 127] = w_pre[i];
    int row0 = blockIdx.x * 16;
    for (int i = tid; i < 16 * 64; i += 256) xs[i >> 6][i & 63] = x[row0 * 64 + i];
    __syncthreads();
    int r = tid >> 4, c0 = (tid & 15) * 8;
    float acc[8] = {};
    for (int k = 0; k < 64; ++k) {
        float xv = xs[r][k];
#pragma unroll
        for (int j = 0; j < 8; ++j) acc[j] += xv * ws[k][c0 + j];
    }
    bf16x8 out;
#pragma unroll
    for (int j = 0; j < 8; ++j) {
        float v = ab[c0 + j] * acc[j] + ab[128 + c0 + j];
        out[j] = (bf16_t)fmaxf(v, 0.f);
    }
    *(bf16x8*)(h + (row0 + r) * 128 + c0) = out;
}

// ---------------- W'^T: wpT[n][k], n in [0,256) outputs, k in [0,128) ----------------
// wpT[n][k] = (n<128) ? w1[k][n] - w2[k][n] : w2[k][n-128]
__global__ __launch_bounds__(256) void k_wprime(const float* __restrict__ w_cn,
        bf16_t* __restrict__ wpT) {
    int k = blockIdx.x;           // 0..127
    int c = threadIdx.x & 127, half = threadIdx.x >> 7;
    if (half == 0)
        wpT[c * 128 + k] = (bf16_t)(w_cn[k * 128 + c] - w_cn[(128 + k) * 128 + c]);
    else
        wpT[(128 + c) * 128 + k] = (bf16_t)(w_cn[(128 + k) * 128 + c]);
}

// ---------------- k_uv: [u|v] = h @ W' (+b_cn on u half), fp16 out ----------------
// Persistent blocks (grid 256); B-frags loaded once as bf16x8 vectors; ~3 tiles/block.
__global__ __launch_bounds__(256) void k_uv(const bf16_t* __restrict__ h,
        const bf16_t* __restrict__ wpT, const float* __restrict__ b_cn,
        f16_t* __restrict__ u, f16_t* __restrict__ v, int N, int ntiles) {
    __shared__ bf16_t at[64 * 136];   // A tile, row stride 136 elements
    __shared__ f16_t ot[64 * 264];    // output staging, row stride 264 elements

    const int tid = threadIdx.x;
    const int lane = tid & 63;
    const int wv = tid >> 6;
    const int n0 = wv * 64;
    const int l16 = lane & 15;
    const int lg = lane >> 4;

    // B fragments: vector loads from transposed W'. k = 32s+8lg+j contiguous.
    bf16x8 bfr[4][4];
#pragma unroll
    for (int s = 0; s < 4; ++s)
#pragma unroll
        for (int c = 0; c < 4; ++c)
            bfr[s][c] = *(const bf16x8*)(wpT + (n0 + 16 * c + l16) * 128 + 32 * s + 8 * lg);

    float bias[4];
#pragma unroll
    for (int c = 0; c < 4; ++c) {
        int n = n0 + 16 * c + l16;
        bias[c] = (n < 128) ? b_cn[n] : 0.f;
    }

    const int sr = tid >> 2, sq = tid & 3;  // staging: 4 threads/row

    for (int tile = blockIdx.x; tile < ntiles; tile += gridDim.x) {
        const int row0 = tile * 64;
        // stage A: 64 rows x 128 bf16 (clamped rows for tail)
        {
            int rg = row0 + sr; if (rg >= N) rg = N - 1;
            const bf16_t* hr = h + (size_t)rg * 128 + sq * 32;
            bf16_t* dr = at + sr * 136 + sq * 32;
#pragma unroll
            for (int c4 = 0; c4 < 4; ++c4)
                *(bf16x8*)(dr + c4 * 8) = *(const bf16x8*)(hr + c4 * 8);
        }
        __syncthreads();

        f32x4 acc[4][4];
#pragma unroll
        for (int c = 0; c < 4; ++c) {
            f32x4 ini = {bias[c], bias[c], bias[c], bias[c]};
#pragma unroll
            for (int rt = 0; rt < 4; ++rt) acc[rt][c] = ini;
        }
#pragma unroll
        for (int s = 0; s < 4; ++s) {
            bf16x8 afr[4];
#pragma unroll
            for (int rt = 0; rt < 4; ++rt)
                afr[rt] = *(const bf16x8*)(at + (rt * 16 + l16) * 136 + 32 * s + 8 * lg);
#pragma unroll
            for (int rt = 0; rt < 4; ++rt)
#pragma unroll
                for (int c = 0; c < 4; ++c)
                    acc[rt][c] = __builtin_amdgcn_mfma_f32_16x16x32_bf16(afr[rt], bfr[s][c], acc[rt][c], 0, 0, 0);
        }

        // regs -> LDS (f16); C/D layout col=lane&15, row=lg*4+reg
#pragma unroll
        for (int rt = 0; rt < 4; ++rt)
#pragma unroll
            for (int c = 0; c < 4; ++c) {
                int n = n0 + 16 * c + l16;
#pragma unroll
                for (int reg = 0; reg < 4; ++reg) {
                    int r = rt * 16 + lg * 4 + reg;
                    ot[r * 264 + n] = (f16_t)acc[rt][c][reg];
                }
            }
        __syncthreads();

        // coalesced copy out
#pragma unroll
        for (int it = 0; it < 8; ++it) {
            int r = wv * 16 + it * 2 + (lane >> 5);
            int cc = (lane & 31) * 8;
            int rg = row0 + r;
            if (rg < N) {
                f16x8 w8 = *(const f16x8*)(ot + r * 264 + cc);
                if (cc < 128) *(f16x8*)(u + (size_t)rg * 128 + cc) = w8;
                else          *(f16x8*)(v + (size_t)rg * 128 + cc - 128) = w8;
            }
        }
        // next stageA writes 'at' (disjoint from 'ot'); sync1 of next iter orders vs this copyout
    }
}

// ---------------- counting sort of edges by g = seg[src[e]] ----------------
__global__ __launch_bounds__(256) void k_hist(const int* __restrict__ src,
        const int* __restrict__ seg, int* __restrict__ gcnt, int E) {
    __shared__ int lh[512];
    int tid = threadIdx.x;
    for (int i = tid; i < 512; i += 256) lh[i] = 0;
    __syncthreads();
    for (int e = blockIdx.x * 256 + tid; e < E; e += gridDim.x * 256)
        atomicAdd(&lh[seg[src[e]]], 1);
    __syncthreads();
    for (int i = tid; i < 512; i += 256)
        if (lh[i]) atomicAdd(&gcnt[i], lh[i]);
}

__global__ __launch_bounds__(512) void k_scan(const int* __restrict__ gcnt,
        int* __restrict__ offs, int* __restrict__ cursor) {
    __shared__ int s[512];
    int tid = threadIdx.x;
    s[tid] = gcnt[tid];
    __syncthreads();
    for (int off = 1; off < 512; off <<= 1) {
        int v = (tid >= off) ? s[tid - off] : 0;
        __syncthreads();
        s[tid] += v;
        __syncthreads();
    }
    offs[tid + 1] = s[tid];
    int ex = tid ? s[tid - 1] : 0;
    if (tid == 0) offs[0] = 0;
    cursor[tid] = ex;
}

__global__ __launch_bounds__(256) void k_scatter(const int* __restrict__ src,
        const int* __restrict__ dst, const int* __restrict__ seg,
        int* __restrict__ cursor, int2* __restrict__ sorted, int E, int CH) {
    __shared__ int lh[512];
    __shared__ int lbase[512];
    int tid = threadIdx.x;
    int e0 = blockIdx.x * CH;
    int e1 = min(E, e0 + CH);
    for (int i = tid; i < 512; i += 256) lh[i] = 0;
    __syncthreads();
    for (int e = e0 + tid; e < e1; e += 256)
        atomicAdd(&lh[seg[src[e]]], 1);
    __syncthreads();
    for (int i = tid; i < 512; i += 256) {
        int c = lh[i];
        lbase[i] = c ? atomicAdd(&cursor[i], c) : 0;
        lh[i] = 0;
    }
    __syncthreads();
    for (int e = e0 + tid; e < e1; e += 256) {
        int si = src[e];
        int g = seg[si];
        int k = atomicAdd(&lh[g], 1);
        sorted[lbase[g] + k] = make_int2(si, dst[e]);
    }
}

// ---------------- k_agg: p[g] = sum over g's edges of relu(u[src]+v[dst]) ----------------
// 4 blocks per graph (grid 4G) for occupancy; block partial -> one atomicAdd per col.
__global__ __launch_bounds__(256) void k_agg(const int2* __restrict__ sorted,
        const int* __restrict__ offs, const f16_t* __restrict__ u,
        const f16_t* __restrict__ v, float* __restrict__ p) {
    const int g = blockIdx.x >> 2;
    const int sp = blockIdx.x & 3;
    const int s0 = offs[g], s1 = offs[g + 1];
    const int tid = threadIdx.x;
    const int lane = tid & 63;
    const int wv = tid >> 6;
    const int sub = lane >> 4;
    const int c0 = (lane & 15) * 8;
    float acc[8] = {};
    for (int base = s0 + (sp * 4 + wv) * 4; base < s1; base += 64) {
        int e = base + sub;
        if (e < s1) {
            int2 pr = sorted[e];
            f16x8 uu = *(const f16x8*)(u + (size_t)pr.x * 128 + c0);
            f16x8 vv = *(const f16x8*)(v + (size_t)pr.y * 128 + c0);
#pragma unroll
            for (int j = 0; j < 8; ++j)
                acc[j] += fmaxf((float)uu[j] + (float)vv[j], 0.f);
        }
    }
#pragma unroll
    for (int j = 0; j < 8; ++j) {
        acc[j] += __shfl_xor(acc[j], 16, 64);
        acc[j] += __shfl_xor(acc[j], 32, 64);
    }
    __shared__ float red[4][128];
    if (lane < 16) {
#pragma unroll
        for (int j = 0; j < 8; ++j) red[wv][c0 + j] = acc[j];
    }
    __syncthreads();
    if (tid < 128) {
        float sum = red[0][tid] + red[1][tid] + red[2][tid] + red[3][tid];
        atomicAdd(&p[g * 128 + tid], sum);
    }
}

// ---------------- Phase C: post MLP + BN + head ----------------
__global__ __launch_bounds__(256) void k_post_gemm(const float* __restrict__ p,
        const float* __restrict__ w_post, const float* __restrict__ b_post,
        float* __restrict__ y, float* __restrict__ stats) {
    int tid = threadIdx.x;
    int row0 = blockIdx.x * 16;
    int col = tid & 127, rg = tid >> 7;
    float acc[8] = {};
    for (int k = 0; k < 128; ++k) {
        float wv = w_post[k * 128 + col];
#pragma unroll
        for (int i = 0; i < 8; ++i) acc[i] += p[(row0 + rg * 8 + i) * 128 + k] * wv;
    }
    float b = b_post[col], s1 = 0.f, s2 = 0.f;
#pragma unroll
    for (int i = 0; i < 8; ++i) {
        float yv = acc[i] + b;
        y[(row0 + rg * 8 + i) * 128 + col] = yv;
        s1 += yv; s2 += yv * yv;
    }
    atomicAdd(&stats[col], s1);
    atomicAdd(&stats[128 + col], s2);
}

__global__ void k_post_finalize(const float* __restrict__ stats, const float* __restrict__ g_post,
                                const float* __restrict__ be_post, float* __restrict__ ab, float invG) {
    int c = threadIdx.x;
    float mu = stats[c] * invG;
    float var = stats[128 + c] * invG - mu * mu;
    float a = g_post[c] * rsqrtf(var + 1e-3f);
    ab[c] = a;
    ab[128 + c] = be_post[c] - mu * a;
}

__global__ __launch_bounds__(256) void k_out(const float* __restrict__ y,
        const float* __restrict__ ab, const float* __restrict__ w_out,
        const float* __restrict__ b_out, float* __restrict__ out) {
    int lane = threadIdx.x & 63;
    int wv = threadIdx.x >> 6;
    int row = blockIdx.x * 4 + wv;
    int c0 = lane * 2;
    float v = 0.f;
#pragma unroll
    for (int j = 0; j < 2; ++j) {
        int c = c0 + j;
        float t = fmaxf(ab[c] * y[row * 128 + c] + ab[128 + c], 0.f);
        v += t * w_out[c];
    }
#pragma unroll
    for (int m = 32; m >= 1; m >>= 1) v += __shfl_xor(v, m, 64);
    if (lane == 0) out[row] = 1.f / (1.f + expf(-(v + b_out[0])));
}

extern "C" void kernel_launch(void* const* d_in, const int* in_sizes, int n_in,
                              void* d_out, int out_size, void* d_ws, size_t ws_size,
                              hipStream_t stream) {
    const float* x      = (const float*)d_in[0];
    const int*   src    = (const int*)d_in[1];
    const int*   dst    = (const int*)d_in[2];
    const int*   seg    = (const int*)d_in[3];
    const float* w_pre  = (const float*)d_in[4];
    const float* b_pre  = (const float*)d_in[5];
    const float* g_pre  = (const float*)d_in[6];
    const float* be_pre = (const float*)d_in[7];
    const float* w_cn   = (const float*)d_in[8];
    const float* b_cn   = (const float*)d_in[9];
    const float* w_post = (const float*)d_in[10];
    const float* b_post = (const float*)d_in[11];
    const float* g_post = (const float*)d_in[12];
    const float* be_post= (const float*)d_in[13];
    const float* w_out  = (const float*)d_in[14];
    const float* b_out  = (const float*)d_in[15];
    const int E = in_sizes[1];
    const int N = in_sizes[3];
    const int G = out_size;

    char* ws = (char*)d_ws;
    float* stats_pre  = (float*)(ws + 0);        // 1KB, zeroed each call
    float* stats_post = (float*)(ws + 1024);     // 1KB, zeroed each call
    int*   gcnt       = (int*)(ws + 2048);       // 2KB, zeroed each call
    float* ab_pre     = (float*)(ws + 4096);
    float* ab_post    = (float*)(ws + 5120);
    int*   offs       = (int*)(ws + 6144);       // 513 ints
    int*   cursor     = (int*)(ws + 10240);      // 512 ints
    bf16_t* wpT       = (bf16_t*)(ws + 12288);   // 64KB, [256][128]
    float* pbuf       = (float*)(ws + 131072);   // 256KB, zeroed each call (atomic accum)
    float* ybuf       = (float*)(ws + 131072 + 262144); // 256KB
    size_t big0 = 1 << 20;
    size_t NB = (((size_t)N * 128 * 2) + 4095) & ~(size_t)4095;   // f16 table bytes
    f16_t* ubuf = (f16_t*)(ws + big0);
    f16_t* vbuf = (f16_t*)(ws + big0 + NB);
    bf16_t* hbuf = (bf16_t*)(ws + big0 + 2 * NB);
    int2* sorted = (int2*)(ws + big0 + 2 * NB);  // aliases hbuf (h dead after k_uv)
    (void)ws_size;

    // zero stats/gcnt + pbuf (atomic accumulators)
    (void)hipMemsetAsync(d_ws, 0, 131072 + 262144, stream);

    int nb_pre = (N + 15) / 16;
    k_pre_stats<<<nb_pre, 256, 0, stream>>>(x, w_pre, b_pre, stats_pre);
    k_pre_finalize<<<1, 128, 0, stream>>>(stats_pre, b_pre, g_pre, be_pre, ab_pre, 1.f / (float)N);
    k_pre_apply<<<nb_pre, 256, 0, stream>>>(x, w_pre, ab_pre, hbuf);
    k_wprime<<<128, 256, 0, stream>>>(w_cn, wpT);
    int ntiles = (N + 63) / 64;
    k_uv<<<256, 256, 0, stream>>>(hbuf, wpT, b_cn, ubuf, vbuf, N, ntiles);
    k_hist<<<512, 256, 0, stream>>>(src, seg, gcnt, E);
    k_scan<<<1, 512, 0, stream>>>(gcnt, offs, cursor);
    int CH = (E + 511) / 512;
    k_scatter<<<512, 256, 0, stream>>>(src, dst, seg, cursor, sorted, E, CH);
    k_agg<<<4 * G, 256, 0, stream>>>(sorted, offs, ubuf, vbuf, pbuf);
    k_post_gemm<<<G / 16, 256, 0, stream>>>(pbuf, w_post, b_post, ybuf, stats_post);
    k_post_finalize<<<1, 128, 0, stream>>>(stats_post, g_post, be_post, ab_post, 1.f / (float)G);
    k_out<<<G / 4, 256, 0, stream>>>(ybuf, ab_post, w_out, b_out, (float*)d_out);
}

// Round 6
// 331.324 us; speedup vs baseline: 3.0408x; 1.4568x over previous
//
#include <hip/hip_runtime.h>
#include <hip/hip_bf16.h>

typedef __bf16 bf16_t;
typedef _Float16 f16_t;
typedef __attribute__((ext_vector_type(8))) __bf16 bf16x8;
typedef __attribute__((ext_vector_type(8))) _Float16 f16x8;
typedef __attribute__((ext_vector_type(4))) _Float16 f16x4;
typedef __attribute__((ext_vector_type(4))) float f32x4;

// ---------------- Phase A: single-pass GEMM y = x@w_pre + b_pre (f16) + col stats ----------------
// Block: 64 rows x 128 cols. Thread: 8 rows x 4 cols register tile.
// Per k-iter: 1 ds_read_b128 (w) + 8 broadcast b32 (x) -> 32 FMA. VALU-bound.
__global__ __launch_bounds__(256) void k_pre_gemm(const float* __restrict__ x,
        const float* __restrict__ w_pre, const float* __restrict__ b_pre,
        f16_t* __restrict__ y, float* __restrict__ stats, int N) {
    __shared__ float ws[64][128];    // 32 KB
    __shared__ float xs[64][64];     // 16 KB
    __shared__ float red[8][2][128]; // 8 KB
    const int tid = threadIdx.x;
    const int row0 = blockIdx.x * 64;

    for (int i = tid; i < 64 * 128; i += 256) ws[i >> 7][i & 127] = w_pre[i];
    {
        int r = tid >> 2, q = tid & 3;
        int rg = row0 + r; if (rg >= N) rg = N - 1;
        const float4* xr = (const float4*)(x + (size_t)rg * 64 + q * 16);
        float4* dr = (float4*)(&xs[r][q * 16]);
#pragma unroll
        for (int j = 0; j < 4; ++j) dr[j] = xr[j];
    }
    __syncthreads();

    const int rg8 = tid >> 5;        // 0..7 row group
    const int c4 = tid & 31;         // col group (4 cols)
    const int c0 = c4 * 4;
    float acc[8][4] = {};
    for (int k = 0; k < 64; ++k) {
        float4 wv = *(const float4*)(&ws[k][c0]);
#pragma unroll
        for (int i = 0; i < 8; ++i) {
            float xv = xs[rg8 * 8 + i][k];
            acc[i][0] += xv * wv.x;
            acc[i][1] += xv * wv.y;
            acc[i][2] += xv * wv.z;
            acc[i][3] += xv * wv.w;
        }
    }

    float bc[4];
#pragma unroll
    for (int j = 0; j < 4; ++j) bc[j] = b_pre[c0 + j];
    float s1[4] = {}, s2[4] = {};
#pragma unroll
    for (int i = 0; i < 8; ++i) {
        int row = row0 + rg8 * 8 + i;
        if (row < N) {
            f16x4 o;
#pragma unroll
            for (int j = 0; j < 4; ++j) {
                float yv = acc[i][j] + bc[j];
                o[j] = (f16_t)yv;
                s1[j] += yv; s2[j] += yv * yv;
            }
            *(f16x4*)(y + (size_t)row * 128 + c0) = o;
        }
    }
#pragma unroll
    for (int j = 0; j < 4; ++j) {
        red[rg8][0][c0 + j] = s1[j];
        red[rg8][1][c0 + j] = s2[j];
    }
    __syncthreads();
    {
        int col = tid & 127, st = tid >> 7;
        float t = 0.f;
#pragma unroll
        for (int g = 0; g < 8; ++g) t += red[g][st][col];
        atomicAdd(&stats[st * 128 + col], t);
    }
}

__global__ void k_pre_finalize(const float* __restrict__ stats,
                               const float* __restrict__ g_pre, const float* __restrict__ be_pre,
                               float* __restrict__ ab, float invN) {
    int c = threadIdx.x;
    float mu = stats[c] * invN;
    float var = stats[128 + c] * invN - mu * mu;
    float a = g_pre[c] * rsqrtf(var + 1e-3f);
    ab[c] = a;
    ab[128 + c] = be_pre[c] - mu * a;
}

// h = bf16(relu(a*y + b)), elementwise over N*128 (8 elems/thread/iter)
__global__ __launch_bounds__(256) void k_apply(const f16_t* __restrict__ y,
        const float* __restrict__ ab, bf16_t* __restrict__ h, int total8) {
    __shared__ float a_s[128], b_s[128];
    int tid = threadIdx.x;
    if (tid < 128) { a_s[tid] = ab[tid]; b_s[tid] = ab[128 + tid]; }
    __syncthreads();
    for (int i = blockIdx.x * 256 + tid; i < total8; i += gridDim.x * 256) {
        f16x8 v = ((const f16x8*)y)[i];
        int c0 = (i * 8) & 127;
        bf16x8 o;
#pragma unroll
        for (int j = 0; j < 8; ++j)
            o[j] = (bf16_t)fmaxf(a_s[c0 + j] * (float)v[j] + b_s[c0 + j], 0.f);
        ((bf16x8*)h)[i] = o;
    }
}

// ---------------- W'^T: wpT[n][k], n in [0,256) outputs, k in [0,128) ----------------
__global__ __launch_bounds__(256) void k_wprime(const float* __restrict__ w_cn,
        bf16_t* __restrict__ wpT) {
    int k = blockIdx.x;           // 0..127
    int c = threadIdx.x & 127, half = threadIdx.x >> 7;
    if (half == 0)
        wpT[c * 128 + k] = (bf16_t)(w_cn[k * 128 + c] - w_cn[(128 + k) * 128 + c]);
    else
        wpT[(128 + c) * 128 + k] = (bf16_t)(w_cn[(128 + k) * 128 + c]);
}

// ---------------- k_uv: [u|v] = h @ W' (+b_cn on u half), fp16 out ----------------
__global__ __launch_bounds__(256) void k_uv(const bf16_t* __restrict__ h,
        const bf16_t* __restrict__ wpT, const float* __restrict__ b_cn,
        f16_t* __restrict__ u, f16_t* __restrict__ v, int N, int ntiles) {
    __shared__ bf16_t at[64 * 136];   // A tile, row stride 136 elements
    __shared__ f16_t ot[64 * 264];    // output staging, row stride 264 elements

    const int tid = threadIdx.x;
    const int lane = tid & 63;
    const int wv = tid >> 6;
    const int n0 = wv * 64;
    const int l16 = lane & 15;
    const int lg = lane >> 4;

    bf16x8 bfr[4][4];
#pragma unroll
    for (int s = 0; s < 4; ++s)
#pragma unroll
        for (int c = 0; c < 4; ++c)
            bfr[s][c] = *(const bf16x8*)(wpT + (n0 + 16 * c + l16) * 128 + 32 * s + 8 * lg);

    float bias[4];
#pragma unroll
    for (int c = 0; c < 4; ++c) {
        int n = n0 + 16 * c + l16;
        bias[c] = (n < 128) ? b_cn[n] : 0.f;
    }

    const int sr = tid >> 2, sq = tid & 3;

    for (int tile = blockIdx.x; tile < ntiles; tile += gridDim.x) {
        const int row0 = tile * 64;
        {
            int rg = row0 + sr; if (rg >= N) rg = N - 1;
            const bf16_t* hr = h + (size_t)rg * 128 + sq * 32;
            bf16_t* dr = at + sr * 136 + sq * 32;
#pragma unroll
            for (int c4 = 0; c4 < 4; ++c4)
                *(bf16x8*)(dr + c4 * 8) = *(const bf16x8*)(hr + c4 * 8);
        }
        __syncthreads();

        f32x4 acc[4][4];
#pragma unroll
        for (int c = 0; c < 4; ++c) {
            f32x4 ini = {bias[c], bias[c], bias[c], bias[c]};
#pragma unroll
            for (int rt = 0; rt < 4; ++rt) acc[rt][c] = ini;
        }
#pragma unroll
        for (int s = 0; s < 4; ++s) {
            bf16x8 afr[4];
#pragma unroll
            for (int rt = 0; rt < 4; ++rt)
                afr[rt] = *(const bf16x8*)(at + (rt * 16 + l16) * 136 + 32 * s + 8 * lg);
#pragma unroll
            for (int rt = 0; rt < 4; ++rt)
#pragma unroll
                for (int c = 0; c < 4; ++c)
                    acc[rt][c] = __builtin_amdgcn_mfma_f32_16x16x32_bf16(afr[rt], bfr[s][c], acc[rt][c], 0, 0, 0);
        }

#pragma unroll
        for (int rt = 0; rt < 4; ++rt)
#pragma unroll
            for (int c = 0; c < 4; ++c) {
                int n = n0 + 16 * c + l16;
#pragma unroll
                for (int reg = 0; reg < 4; ++reg) {
                    int r = rt * 16 + lg * 4 + reg;
                    ot[r * 264 + n] = (f16_t)acc[rt][c][reg];
                }
            }
        __syncthreads();

#pragma unroll
        for (int it = 0; it < 8; ++it) {
            int r = wv * 16 + it * 2 + (lane >> 5);
            int cc = (lane & 31) * 8;
            int rg = row0 + r;
            if (rg < N) {
                f16x8 w8 = *(const f16x8*)(ot + r * 264 + cc);
                if (cc < 128) *(f16x8*)(u + (size_t)rg * 128 + cc) = w8;
                else          *(f16x8*)(v + (size_t)rg * 128 + cc - 128) = w8;
            }
        }
    }
}

// ---------------- counting sort of edges by g = seg[src[e]] ----------------
__global__ __launch_bounds__(256) void k_hist(const int* __restrict__ src,
        const int* __restrict__ seg, int* __restrict__ gcnt, int E) {
    __shared__ int lh[512];
    int tid = threadIdx.x;
    for (int i = tid; i < 512; i += 256) lh[i] = 0;
    __syncthreads();
    for (int e = blockIdx.x * 256 + tid; e < E; e += gridDim.x * 256)
        atomicAdd(&lh[seg[src[e]]], 1);
    __syncthreads();
    for (int i = tid; i < 512; i += 256)
        if (lh[i]) atomicAdd(&gcnt[i], lh[i]);
}

__global__ __launch_bounds__(512) void k_scan(const int* __restrict__ gcnt,
        int* __restrict__ offs, int* __restrict__ cursor) {
    __shared__ int s[512];
    int tid = threadIdx.x;
    s[tid] = gcnt[tid];
    __syncthreads();
    for (int off = 1; off < 512; off <<= 1) {
        int v = (tid >= off) ? s[tid - off] : 0;
        __syncthreads();
        s[tid] += v;
        __syncthreads();
    }
    offs[tid + 1] = s[tid];
    int ex = tid ? s[tid - 1] : 0;
    if (tid == 0) offs[0] = 0;
    cursor[tid] = ex;
}

__global__ __launch_bounds__(256) void k_scatter(const int* __restrict__ src,
        const int* __restrict__ dst, const int* __restrict__ seg,
        int* __restrict__ cursor, int2* __restrict__ sorted, int E, int CH) {
    __shared__ int lh[512];
    __shared__ int lbase[512];
    int tid = threadIdx.x;
    int e0 = blockIdx.x * CH;
    int e1 = min(E, e0 + CH);
    for (int i = tid; i < 512; i += 256) lh[i] = 0;
    __syncthreads();
    for (int e = e0 + tid; e < e1; e += 256)
        atomicAdd(&lh[seg[src[e]]], 1);
    __syncthreads();
    for (int i = tid; i < 512; i += 256) {
        int c = lh[i];
        lbase[i] = c ? atomicAdd(&cursor[i], c) : 0;
        lh[i] = 0;
    }
    __syncthreads();
    for (int e = e0 + tid; e < e1; e += 256) {
        int si = src[e];
        int g = seg[si];
        int k = atomicAdd(&lh[g], 1);
        sorted[lbase[g] + k] = make_int2(si, dst[e]);
    }
}

// ---------------- k_agg: p[g] = sum over g's edges of relu(u[src]+v[dst]) ----------------
__global__ __launch_bounds__(256) void k_agg(const int2* __restrict__ sorted,
        const int* __restrict__ offs, const f16_t* __restrict__ u,
        const f16_t* __restrict__ v, float* __restrict__ p) {
    const int g = blockIdx.x >> 2;
    const int sp = blockIdx.x & 3;
    const int s0 = offs[g], s1 = offs[g + 1];
    const int tid = threadIdx.x;
    const int lane = tid & 63;
    const int wv = tid >> 6;
    const int sub = lane >> 4;
    const int c0 = (lane & 15) * 8;
    float acc[8] = {};
    for (int base = s0 + (sp * 4 + wv) * 4; base < s1; base += 64) {
        int e = base + sub;
        if (e < s1) {
            int2 pr = sorted[e];
            f16x8 uu = *(const f16x8*)(u + (size_t)pr.x * 128 + c0);
            f16x8 vv = *(const f16x8*)(v + (size_t)pr.y * 128 + c0);
#pragma unroll
            for (int j = 0; j < 8; ++j)
                acc[j] += fmaxf((float)uu[j] + (float)vv[j], 0.f);
        }
    }
#pragma unroll
    for (int j = 0; j < 8; ++j) {
        acc[j] += __shfl_xor(acc[j], 16, 64);
        acc[j] += __shfl_xor(acc[j], 32, 64);
    }
    __shared__ float red[4][128];
    if (lane < 16) {
#pragma unroll
        for (int j = 0; j < 8; ++j) red[wv][c0 + j] = acc[j];
    }
    __syncthreads();
    if (tid < 128) {
        float sum = red[0][tid] + red[1][tid] + red[2][tid] + red[3][tid];
        atomicAdd(&p[g * 128 + tid], sum);
    }
}

// ---------------- Phase C: post MLP + BN + head ----------------
__global__ __launch_bounds__(256) void k_post_gemm(const float* __restrict__ p,
        const float* __restrict__ w_post, const float* __restrict__ b_post,
        float* __restrict__ y, float* __restrict__ stats) {
    int tid = threadIdx.x;
    int row0 = blockIdx.x * 16;
    int col = tid & 127, rg = tid >> 7;
    float acc[8] = {};
    for (int k = 0; k < 128; ++k) {
        float wv = w_post[k * 128 + col];
#pragma unroll
        for (int i = 0; i < 8; ++i) acc[i] += p[(row0 + rg * 8 + i) * 128 + k] * wv;
    }
    float b = b_post[col], s1 = 0.f, s2 = 0.f;
#pragma unroll
    for (int i = 0; i < 8; ++i) {
        float yv = acc[i] + b;
        y[(row0 + rg * 8 + i) * 128 + col] = yv;
        s1 += yv; s2 += yv * yv;
    }
    atomicAdd(&stats[col], s1);
    atomicAdd(&stats[128 + col], s2);
}

__global__ void k_post_finalize(const float* __restrict__ stats, const float* __restrict__ g_post,
                                const float* __restrict__ be_post, float* __restrict__ ab, float invG) {
    int c = threadIdx.x;
    float mu = stats[c] * invG;
    float var = stats[128 + c] * invG - mu * mu;
    float a = g_post[c] * rsqrtf(var + 1e-3f);
    ab[c] = a;
    ab[128 + c] = be_post[c] - mu * a;
}

__global__ __launch_bounds__(256) void k_out(const float* __restrict__ y,
        const float* __restrict__ ab, const float* __restrict__ w_out,
        const float* __restrict__ b_out, float* __restrict__ out) {
    int lane = threadIdx.x & 63;
    int wv = threadIdx.x >> 6;
    int row = blockIdx.x * 4 + wv;
    int c0 = lane * 2;
    float v = 0.f;
#pragma unroll
    for (int j = 0; j < 2; ++j) {
        int c = c0 + j;
        float t = fmaxf(ab[c] * y[row * 128 + c] + ab[128 + c], 0.f);
        v += t * w_out[c];
    }
#pragma unroll
    for (int m = 32; m >= 1; m >>= 1) v += __shfl_xor(v, m, 64);
    if (lane == 0) out[row] = 1.f / (1.f + expf(-(v + b_out[0])));
}

extern "C" void kernel_launch(void* const* d_in, const int* in_sizes, int n_in,
                              void* d_out, int out_size, void* d_ws, size_t ws_size,
                              hipStream_t stream) {
    const float* x      = (const float*)d_in[0];
    const int*   src    = (const int*)d_in[1];
    const int*   dst    = (const int*)d_in[2];
    const int*   seg    = (const int*)d_in[3];
    const float* w_pre  = (const float*)d_in[4];
    const float* b_pre  = (const float*)d_in[5];
    const float* g_pre  = (const float*)d_in[6];
    const float* be_pre = (const float*)d_in[7];
    const float* w_cn   = (const float*)d_in[8];
    const float* b_cn   = (const float*)d_in[9];
    const float* w_post = (const float*)d_in[10];
    const float* b_post = (const float*)d_in[11];
    const float* g_post = (const float*)d_in[12];
    const float* be_post= (const float*)d_in[13];
    const float* w_out  = (const float*)d_in[14];
    const float* b_out  = (const float*)d_in[15];
    const int E = in_sizes[1];
    const int N = in_sizes[3];
    const int G = out_size;

    char* ws = (char*)d_ws;
    float* stats_pre  = (float*)(ws + 0);        // 1KB, zeroed each call
    float* stats_post = (float*)(ws + 1024);     // 1KB, zeroed each call
    int*   gcnt       = (int*)(ws + 2048);       // 2KB, zeroed each call
    float* ab_pre     = (float*)(ws + 4096);
    float* ab_post    = (float*)(ws + 5120);
    int*   offs       = (int*)(ws + 6144);       // 513 ints
    int*   cursor     = (int*)(ws + 10240);      // 512 ints
    bf16_t* wpT       = (bf16_t*)(ws + 12288);   // 64KB, [256][128]
    float* pbuf       = (float*)(ws + 131072);   // 256KB, zeroed (atomic accum)
    float* ybuf       = (float*)(ws + 131072 + 262144); // 256KB
    size_t big0 = 1 << 20;
    size_t NB = (((size_t)N * 128 * 2) + 4095) & ~(size_t)4095;   // f16 table bytes
    f16_t* ubuf = (f16_t*)(ws + big0);
    f16_t* vbuf = (f16_t*)(ws + big0 + NB);
    bf16_t* hbuf = (bf16_t*)(ws + big0 + 2 * NB);
    int2* sorted = (int2*)(ws + big0 + 2 * NB);  // aliases hbuf (h dead after k_agg inputs built)
    f16_t* ypre  = (f16_t*)(ws + big0 + 3 * NB); // f16 y (pre-BN), N*128
    (void)ws_size;

    // zero stats/gcnt + pbuf (atomic accumulators)
    (void)hipMemsetAsync(d_ws, 0, 131072 + 262144, stream);

    int nb64 = (N + 63) / 64;
    k_pre_gemm<<<nb64, 256, 0, stream>>>(x, w_pre, b_pre, ypre, stats_pre, N);
    k_pre_finalize<<<1, 128, 0, stream>>>(stats_pre, g_pre, be_pre, ab_pre, 1.f / (float)N);
    k_apply<<<1024, 256, 0, stream>>>(ypre, ab_pre, hbuf, N * 128 / 8);
    k_wprime<<<128, 256, 0, stream>>>(w_cn, wpT);
    k_uv<<<256, 256, 0, stream>>>(hbuf, wpT, b_cn, ubuf, vbuf, N, nb64);
    k_hist<<<512, 256, 0, stream>>>(src, seg, gcnt, E);
    k_scan<<<1, 512, 0, stream>>>(gcnt, offs, cursor);
    int CH = (E + 511) / 512;
    k_scatter<<<512, 256, 0, stream>>>(src, dst, seg, cursor, sorted, E, CH);
    k_agg<<<4 * G, 256, 0, stream>>>(sorted, offs, ubuf, vbuf, pbuf);
    k_post_gemm<<<G / 16, 256, 0, stream>>>(pbuf, w_post, b_post, ybuf, stats_post);
    k_post_finalize<<<1, 128, 0, stream>>>(stats_post, g_post, be_post, ab_post, 1.f / (float)G);
    k_out<<<G / 4, 256, 0, stream>>>(ybuf, ab_post, w_out, b_out, (float*)d_out);
}

// Round 7
// 322.864 us; speedup vs baseline: 3.1204x; 1.0262x over previous
//
#include <hip/hip_runtime.h>
#include <hip/hip_bf16.h>

typedef __bf16 bf16_t;
typedef _Float16 f16_t;
typedef __attribute__((ext_vector_type(8))) __bf16 bf16x8;
typedef __attribute__((ext_vector_type(8))) _Float16 f16x8;
typedef __attribute__((ext_vector_type(4))) _Float16 f16x4;
typedef __attribute__((ext_vector_type(4))) float f32x4;

// ---------------- Phase A: single-pass GEMM y = x@w_pre + b_pre (f16) + col stats ----------------
__global__ __launch_bounds__(256) void k_pre_gemm(const float* __restrict__ x,
        const float* __restrict__ w_pre, const float* __restrict__ b_pre,
        f16_t* __restrict__ y, float* __restrict__ stats, int N) {
    __shared__ float ws[64][128];    // 32 KB
    __shared__ float xs[64][64];     // 16 KB
    __shared__ float red[8][2][128]; // 8 KB
    const int tid = threadIdx.x;
    const int row0 = blockIdx.x * 64;

    for (int i = tid; i < 64 * 128; i += 256) ws[i >> 7][i & 127] = w_pre[i];
    {
        int r = tid >> 2, q = tid & 3;
        int rg = row0 + r; if (rg >= N) rg = N - 1;
        const float4* xr = (const float4*)(x + (size_t)rg * 64 + q * 16);
        float4* dr = (float4*)(&xs[r][q * 16]);
#pragma unroll
        for (int j = 0; j < 4; ++j) dr[j] = xr[j];
    }
    __syncthreads();

    const int rg8 = tid >> 5;
    const int c0 = (tid & 31) * 4;
    float acc[8][4] = {};
    for (int k = 0; k < 64; ++k) {
        float4 wv = *(const float4*)(&ws[k][c0]);
#pragma unroll
        for (int i = 0; i < 8; ++i) {
            float xv = xs[rg8 * 8 + i][k];
            acc[i][0] += xv * wv.x;
            acc[i][1] += xv * wv.y;
            acc[i][2] += xv * wv.z;
            acc[i][3] += xv * wv.w;
        }
    }

    float bc[4];
#pragma unroll
    for (int j = 0; j < 4; ++j) bc[j] = b_pre[c0 + j];
    float s1[4] = {}, s2[4] = {};
#pragma unroll
    for (int i = 0; i < 8; ++i) {
        int row = row0 + rg8 * 8 + i;
        if (row < N) {
            f16x4 o;
#pragma unroll
            for (int j = 0; j < 4; ++j) {
                float yv = acc[i][j] + bc[j];
                o[j] = (f16_t)yv;
                s1[j] += yv; s2[j] += yv * yv;
            }
            *(f16x4*)(y + (size_t)row * 128 + c0) = o;
        }
    }
#pragma unroll
    for (int j = 0; j < 4; ++j) {
        red[rg8][0][c0 + j] = s1[j];
        red[rg8][1][c0 + j] = s2[j];
    }
    __syncthreads();
    {
        int col = tid & 127, st = tid >> 7;
        float t = 0.f;
#pragma unroll
        for (int g = 0; g < 8; ++g) t += red[g][st][col];
        atomicAdd(&stats[st * 128 + col], t);
    }
}

__global__ void k_pre_finalize(const float* __restrict__ stats,
                               const float* __restrict__ g_pre, const float* __restrict__ be_pre,
                               float* __restrict__ ab, float invN) {
    int c = threadIdx.x;
    float mu = stats[c] * invN;
    float var = stats[128 + c] * invN - mu * mu;
    float a = g_pre[c] * rsqrtf(var + 1e-3f);
    ab[c] = a;
    ab[128 + c] = be_pre[c] - mu * a;
}

// h = bf16(relu(a*y + b)), elementwise
__global__ __launch_bounds__(256) void k_apply(const f16_t* __restrict__ y,
        const float* __restrict__ ab, bf16_t* __restrict__ h, int total8) {
    __shared__ float a_s[128], b_s[128];
    int tid = threadIdx.x;
    if (tid < 128) { a_s[tid] = ab[tid]; b_s[tid] = ab[128 + tid]; }
    __syncthreads();
    for (int i = blockIdx.x * 256 + tid; i < total8; i += gridDim.x * 256) {
        f16x8 v = ((const f16x8*)y)[i];
        int c0 = (i * 8) & 127;
        bf16x8 o;
#pragma unroll
        for (int j = 0; j < 8; ++j)
            o[j] = (bf16_t)fmaxf(a_s[c0 + j] * (float)v[j] + b_s[c0 + j], 0.f);
        ((bf16x8*)h)[i] = o;
    }
}

// ---------------- W'^T: wpT[n][k] ----------------
__global__ __launch_bounds__(256) void k_wprime(const float* __restrict__ w_cn,
        bf16_t* __restrict__ wpT) {
    int k = blockIdx.x;
    int c = threadIdx.x & 127, half = threadIdx.x >> 7;
    if (half == 0)
        wpT[c * 128 + k] = (bf16_t)(w_cn[k * 128 + c] - w_cn[(128 + k) * 128 + c]);
    else
        wpT[(128 + c) * 128 + k] = (bf16_t)(w_cn[(128 + k) * 128 + c]);
}

// ---------------- k_uv: [u|v] = h @ W' (+b_cn on u half) -> group-major f16 [4][N][32] ----------------
__global__ __launch_bounds__(256) void k_uv(const bf16_t* __restrict__ h,
        const bf16_t* __restrict__ wpT, const float* __restrict__ b_cn,
        f16_t* __restrict__ u, f16_t* __restrict__ v, int N, int ntiles) {
    __shared__ bf16_t at[64 * 136];
    __shared__ f16_t ot[64 * 264];

    const int tid = threadIdx.x;
    const int lane = tid & 63;
    const int wv = tid >> 6;
    const int n0 = wv * 64;
    const int l16 = lane & 15;
    const int lg = lane >> 4;

    bf16x8 bfr[4][4];
#pragma unroll
    for (int s = 0; s < 4; ++s)
#pragma unroll
        for (int c = 0; c < 4; ++c)
            bfr[s][c] = *(const bf16x8*)(wpT + (n0 + 16 * c + l16) * 128 + 32 * s + 8 * lg);

    float bias[4];
#pragma unroll
    for (int c = 0; c < 4; ++c) {
        int n = n0 + 16 * c + l16;
        bias[c] = (n < 128) ? b_cn[n] : 0.f;
    }

    const int sr = tid >> 2, sq = tid & 3;

    for (int tile = blockIdx.x; tile < ntiles; tile += gridDim.x) {
        const int row0 = tile * 64;
        {
            int rg = row0 + sr; if (rg >= N) rg = N - 1;
            const bf16_t* hr = h + (size_t)rg * 128 + sq * 32;
            bf16_t* dr = at + sr * 136 + sq * 32;
#pragma unroll
            for (int c4 = 0; c4 < 4; ++c4)
                *(bf16x8*)(dr + c4 * 8) = *(const bf16x8*)(hr + c4 * 8);
        }
        __syncthreads();

        f32x4 acc[4][4];
#pragma unroll
        for (int c = 0; c < 4; ++c) {
            f32x4 ini = {bias[c], bias[c], bias[c], bias[c]};
#pragma unroll
            for (int rt = 0; rt < 4; ++rt) acc[rt][c] = ini;
        }
#pragma unroll
        for (int s = 0; s < 4; ++s) {
            bf16x8 afr[4];
#pragma unroll
            for (int rt = 0; rt < 4; ++rt)
                afr[rt] = *(const bf16x8*)(at + (rt * 16 + l16) * 136 + 32 * s + 8 * lg);
#pragma unroll
            for (int rt = 0; rt < 4; ++rt)
#pragma unroll
                for (int c = 0; c < 4; ++c)
                    acc[rt][c] = __builtin_amdgcn_mfma_f32_16x16x32_bf16(afr[rt], bfr[s][c], acc[rt][c], 0, 0, 0);
        }

#pragma unroll
        for (int rt = 0; rt < 4; ++rt)
#pragma unroll
            for (int c = 0; c < 4; ++c) {
                int n = n0 + 16 * c + l16;
#pragma unroll
                for (int reg = 0; reg < 4; ++reg) {
                    int r = rt * 16 + lg * 4 + reg;
                    ot[r * 264 + n] = (f16_t)acc[rt][c][reg];
                }
            }
        __syncthreads();

        // copy out to group-major [4][N][32]
#pragma unroll
        for (int it = 0; it < 8; ++it) {
            int r = wv * 16 + it * 2 + (lane >> 5);
            int cc = (lane & 31) * 8;
            int rg = row0 + r;
            if (rg < N) {
                f16x8 w8 = *(const f16x8*)(ot + r * 264 + cc);
                if (cc < 128) {
                    int cg = cc >> 5, col = cc & 31;
                    *(f16x8*)(u + ((size_t)cg * N + rg) * 32 + col) = w8;
                } else {
                    int cv = cc - 128;
                    int cg = cv >> 5, col = cv & 31;
                    *(f16x8*)(v + ((size_t)cg * N + rg) * 32 + col) = w8;
                }
            }
        }
    }
}

// ---------------- counting sort of edges by g = seg[src[e]] ----------------
__global__ __launch_bounds__(256) void k_hist(const int* __restrict__ src,
        const int* __restrict__ seg, int* __restrict__ gcnt, int E) {
    __shared__ int lh[512];
    int tid = threadIdx.x;
    for (int i = tid; i < 512; i += 256) lh[i] = 0;
    __syncthreads();
    for (int e = blockIdx.x * 256 + tid; e < E; e += gridDim.x * 256)
        atomicAdd(&lh[seg[src[e]]], 1);
    __syncthreads();
    for (int i = tid; i < 512; i += 256)
        if (lh[i]) atomicAdd(&gcnt[i], lh[i]);
}

__global__ __launch_bounds__(512) void k_scan(const int* __restrict__ gcnt,
        int* __restrict__ offs, int* __restrict__ cursor) {
    __shared__ int s[512];
    int tid = threadIdx.x;
    s[tid] = gcnt[tid];
    __syncthreads();
    for (int off = 1; off < 512; off <<= 1) {
        int v = (tid >= off) ? s[tid - off] : 0;
        __syncthreads();
        s[tid] += v;
        __syncthreads();
    }
    offs[tid + 1] = s[tid];
    int ex = tid ? s[tid - 1] : 0;
    if (tid == 0) offs[0] = 0;
    cursor[tid] = ex;
}

__global__ __launch_bounds__(256) void k_scatter(const int* __restrict__ src,
        const int* __restrict__ dst, const int* __restrict__ seg,
        int* __restrict__ cursor, int2* __restrict__ sorted, int E, int CH) {
    __shared__ int lh[512];
    __shared__ int lbase[512];
    int tid = threadIdx.x;
    int e0 = blockIdx.x * CH;
    int e1 = min(E, e0 + CH);
    for (int i = tid; i < 512; i += 256) lh[i] = 0;
    __syncthreads();
    for (int e = e0 + tid; e < e1; e += 256)
        atomicAdd(&lh[seg[src[e]]], 1);
    __syncthreads();
    for (int i = tid; i < 512; i += 256) {
        int c = lh[i];
        lbase[i] = c ? atomicAdd(&cursor[i], c) : 0;
        lh[i] = 0;
    }
    __syncthreads();
    for (int e = e0 + tid; e < e1; e += 256) {
        int si = src[e];
        int g = seg[si];
        int k = atomicAdd(&lh[g], 1);
        sorted[lbase[g] + k] = make_int2(si, dst[e]);
    }
}

// ---------------- k_agg_cg: one 32-col group per launch; v working set 3.2MB -> L2-resident ----------------
// Block: (graph g, span sp). Wave: 16 edges x (4 lanes x 8 cols). 4 blocks/graph.
__global__ __launch_bounds__(256) void k_agg_cg(const int2* __restrict__ sorted,
        const int* __restrict__ offs, const f16_t* __restrict__ u,
        const f16_t* __restrict__ v, float* __restrict__ p, int N, int cg) {
    const int g = blockIdx.x >> 2;
    const int sp = blockIdx.x & 3;
    const int s0 = offs[g], s1 = offs[g + 1];
    const int tid = threadIdx.x;
    const int lane = tid & 63;
    const int wv = tid >> 6;
    const int sub = lane >> 2;          // 16 edges per wave
    const int c0 = (lane & 3) * 8;      // 8 cols per lane
    const f16_t* ug = u + (size_t)cg * N * 32;
    const f16_t* vg = v + (size_t)cg * N * 32;
    float acc[8] = {};
    for (int base = s0 + (sp * 4 + wv) * 16; base < s1; base += 256) {
        int e = base + sub;
        if (e < s1) {
            int2 pr = sorted[e];
            f16x8 uu = *(const f16x8*)(ug + (size_t)pr.x * 32 + c0);
            f16x8 vv = *(const f16x8*)(vg + (size_t)pr.y * 32 + c0);
#pragma unroll
            for (int j = 0; j < 8; ++j)
                acc[j] += fmaxf((float)uu[j] + (float)vv[j], 0.f);
        }
    }
#pragma unroll
    for (int j = 0; j < 8; ++j) {
        acc[j] += __shfl_xor(acc[j], 4, 64);
        acc[j] += __shfl_xor(acc[j], 8, 64);
        acc[j] += __shfl_xor(acc[j], 16, 64);
        acc[j] += __shfl_xor(acc[j], 32, 64);
    }
    __shared__ float red[4][4][8];
    if (lane < 4) {
#pragma unroll
        for (int j = 0; j < 8; ++j) red[wv][lane][j] = acc[j];
    }
    __syncthreads();
    if (tid < 32) {
        int cs = tid >> 3, j = tid & 7;
        float s = red[0][cs][j] + red[1][cs][j] + red[2][cs][j] + red[3][cs][j];
        atomicAdd(&p[g * 128 + cg * 32 + cs * 8 + j], s);
    }
}

// ---------------- Phase C: post MLP + BN + head ----------------
__global__ __launch_bounds__(256) void k_post_gemm(const float* __restrict__ p,
        const float* __restrict__ w_post, const float* __restrict__ b_post,
        float* __restrict__ y, float* __restrict__ stats) {
    int tid = threadIdx.x;
    int row0 = blockIdx.x * 16;
    int col = tid & 127, rg = tid >> 7;
    float acc[8] = {};
    for (int k = 0; k < 128; ++k) {
        float wv = w_post[k * 128 + col];
#pragma unroll
        for (int i = 0; i < 8; ++i) acc[i] += p[(row0 + rg * 8 + i) * 128 + k] * wv;
    }
    float b = b_post[col], s1 = 0.f, s2 = 0.f;
#pragma unroll
    for (int i = 0; i < 8; ++i) {
        float yv = acc[i] + b;
        y[(row0 + rg * 8 + i) * 128 + col] = yv;
        s1 += yv; s2 += yv * yv;
    }
    atomicAdd(&stats[col], s1);
    atomicAdd(&stats[128 + col], s2);
}

__global__ void k_post_finalize(const float* __restrict__ stats, const float* __restrict__ g_post,
                                const float* __restrict__ be_post, float* __restrict__ ab, float invG) {
    int c = threadIdx.x;
    float mu = stats[c] * invG;
    float var = stats[128 + c] * invG - mu * mu;
    float a = g_post[c] * rsqrtf(var + 1e-3f);
    ab[c] = a;
    ab[128 + c] = be_post[c] - mu * a;
}

__global__ __launch_bounds__(256) void k_out(const float* __restrict__ y,
        const float* __restrict__ ab, const float* __restrict__ w_out,
        const float* __restrict__ b_out, float* __restrict__ out) {
    int lane = threadIdx.x & 63;
    int wv = threadIdx.x >> 6;
    int row = blockIdx.x * 4 + wv;
    int c0 = lane * 2;
    float v = 0.f;
#pragma unroll
    for (int j = 0; j < 2; ++j) {
        int c = c0 + j;
        float t = fmaxf(ab[c] * y[row * 128 + c] + ab[128 + c], 0.f);
        v += t * w_out[c];
    }
#pragma unroll
    for (int m = 32; m >= 1; m >>= 1) v += __shfl_xor(v, m, 64);
    if (lane == 0) out[row] = 1.f / (1.f + expf(-(v + b_out[0])));
}

extern "C" void kernel_launch(void* const* d_in, const int* in_sizes, int n_in,
                              void* d_out, int out_size, void* d_ws, size_t ws_size,
                              hipStream_t stream) {
    const float* x      = (const float*)d_in[0];
    const int*   src    = (const int*)d_in[1];
    const int*   dst    = (const int*)d_in[2];
    const int*   seg    = (const int*)d_in[3];
    const float* w_pre  = (const float*)d_in[4];
    const float* b_pre  = (const float*)d_in[5];
    const float* g_pre  = (const float*)d_in[6];
    const float* be_pre = (const float*)d_in[7];
    const float* w_cn   = (const float*)d_in[8];
    const float* b_cn   = (const float*)d_in[9];
    const float* w_post = (const float*)d_in[10];
    const float* b_post = (const float*)d_in[11];
    const float* g_post = (const float*)d_in[12];
    const float* be_post= (const float*)d_in[13];
    const float* w_out  = (const float*)d_in[14];
    const float* b_out  = (const float*)d_in[15];
    const int E = in_sizes[1];
    const int N = in_sizes[3];
    const int G = out_size;

    char* ws = (char*)d_ws;
    float* stats_pre  = (float*)(ws + 0);        // zeroed each call
    float* stats_post = (float*)(ws + 1024);     // zeroed each call
    int*   gcnt       = (int*)(ws + 2048);       // zeroed each call
    float* ab_pre     = (float*)(ws + 4096);
    float* ab_post    = (float*)(ws + 5120);
    int*   offs       = (int*)(ws + 6144);
    int*   cursor     = (int*)(ws + 10240);
    bf16_t* wpT       = (bf16_t*)(ws + 12288);   // 64KB
    float* pbuf       = (float*)(ws + 131072);   // 256KB, zeroed (atomic accum)
    float* ybuf       = (float*)(ws + 131072 + 262144);
    size_t big0 = 1 << 20;
    size_t NB = (((size_t)N * 128 * 2) + 4095) & ~(size_t)4095;
    f16_t* ubuf = (f16_t*)(ws + big0);            // [4][N][32] f16
    f16_t* vbuf = (f16_t*)(ws + big0 + NB);       // [4][N][32] f16
    bf16_t* hbuf = (bf16_t*)(ws + big0 + 2 * NB);
    int2* sorted = (int2*)(ws + big0 + 2 * NB);   // aliases hbuf (h dead before scatter)
    f16_t* ypre  = (f16_t*)(ws + big0 + 3 * NB);
    (void)ws_size;

    (void)hipMemsetAsync(d_ws, 0, 131072 + 262144, stream);

    int nb64 = (N + 63) / 64;
    k_pre_gemm<<<nb64, 256, 0, stream>>>(x, w_pre, b_pre, ypre, stats_pre, N);
    k_pre_finalize<<<1, 128, 0, stream>>>(stats_pre, g_pre, be_pre, ab_pre, 1.f / (float)N);
    k_apply<<<1024, 256, 0, stream>>>(ypre, ab_pre, hbuf, N * 128 / 8);
    k_wprime<<<128, 256, 0, stream>>>(w_cn, wpT);
    k_uv<<<256, 256, 0, stream>>>(hbuf, wpT, b_cn, ubuf, vbuf, N, nb64);
    k_hist<<<512, 256, 0, stream>>>(src, seg, gcnt, E);
    k_scan<<<1, 512, 0, stream>>>(gcnt, offs, cursor);
    int CH = (E + 511) / 512;
    k_scatter<<<512, 256, 0, stream>>>(src, dst, seg, cursor, sorted, E, CH);
    for (int cg = 0; cg < 4; ++cg)
        k_agg_cg<<<4 * G, 256, 0, stream>>>(sorted, offs, ubuf, vbuf, pbuf, N, cg);
    k_post_gemm<<<G / 16, 256, 0, stream>>>(pbuf, w_post, b_post, ybuf, stats_post);
    k_post_finalize<<<1, 128, 0, stream>>>(stats_post, g_post, be_post, ab_post, 1.f / (float)G);
    k_out<<<G / 4, 256, 0, stream>>>(ybuf, ab_post, w_out, b_out, (float*)d_out);
}

// Round 8
// 292.041 us; speedup vs baseline: 3.4498x; 1.1055x over previous
//
#include <hip/hip_runtime.h>
#include <hip/hip_bf16.h>

typedef __bf16 bf16_t;
typedef _Float16 f16_t;
typedef __attribute__((ext_vector_type(8))) __bf16 bf16x8;
typedef __attribute__((ext_vector_type(8))) _Float16 f16x8;
typedef __attribute__((ext_vector_type(4))) _Float16 f16x4;
typedef __attribute__((ext_vector_type(4))) float f32x4;

#define SC_CAP 3072   // edges per scatter block (LDS-cached)

// ---------------- Phase A: single-pass GEMM y = x@w_pre + b_pre (f16) + col stats ----------------
__global__ __launch_bounds__(256) void k_pre_gemm(const float* __restrict__ x,
        const float* __restrict__ w_pre, const float* __restrict__ b_pre,
        f16_t* __restrict__ y, float* __restrict__ stats, int N) {
    __shared__ float ws[64][128];
    __shared__ float xs[64][64];
    __shared__ float red[8][2][128];
    const int tid = threadIdx.x;
    const int row0 = blockIdx.x * 64;

    for (int i = tid; i < 64 * 128; i += 256) ws[i >> 7][i & 127] = w_pre[i];
    {
        int r = tid >> 2, q = tid & 3;
        int rg = row0 + r; if (rg >= N) rg = N - 1;
        const float4* xr = (const float4*)(x + (size_t)rg * 64 + q * 16);
        float4* dr = (float4*)(&xs[r][q * 16]);
#pragma unroll
        for (int j = 0; j < 4; ++j) dr[j] = xr[j];
    }
    __syncthreads();

    const int rg8 = tid >> 5;
    const int c0 = (tid & 31) * 4;
    float acc[8][4] = {};
    for (int k = 0; k < 64; ++k) {
        float4 wv = *(const float4*)(&ws[k][c0]);
#pragma unroll
        for (int i = 0; i < 8; ++i) {
            float xv = xs[rg8 * 8 + i][k];
            acc[i][0] += xv * wv.x;
            acc[i][1] += xv * wv.y;
            acc[i][2] += xv * wv.z;
            acc[i][3] += xv * wv.w;
        }
    }

    float bc[4];
#pragma unroll
    for (int j = 0; j < 4; ++j) bc[j] = b_pre[c0 + j];
    float s1[4] = {}, s2[4] = {};
#pragma unroll
    for (int i = 0; i < 8; ++i) {
        int row = row0 + rg8 * 8 + i;
        if (row < N) {
            f16x4 o;
#pragma unroll
            for (int j = 0; j < 4; ++j) {
                float yv = acc[i][j] + bc[j];
                o[j] = (f16_t)yv;
                s1[j] += yv; s2[j] += yv * yv;
            }
            *(f16x4*)(y + (size_t)row * 128 + c0) = o;
        }
    }
#pragma unroll
    for (int j = 0; j < 4; ++j) {
        red[rg8][0][c0 + j] = s1[j];
        red[rg8][1][c0 + j] = s2[j];
    }
    __syncthreads();
    {
        int col = tid & 127, st = tid >> 7;
        float t = 0.f;
#pragma unroll
        for (int g = 0; g < 8; ++g) t += red[g][st][col];
        atomicAdd(&stats[st * 128 + col], t);
    }
}

__global__ void k_pre_finalize(const float* __restrict__ stats,
                               const float* __restrict__ g_pre, const float* __restrict__ be_pre,
                               float* __restrict__ ab, float invN) {
    int c = threadIdx.x;
    float mu = stats[c] * invN;
    float var = stats[128 + c] * invN - mu * mu;
    float a = g_pre[c] * rsqrtf(var + 1e-3f);
    ab[c] = a;
    ab[128 + c] = be_pre[c] - mu * a;
}

__global__ __launch_bounds__(256) void k_apply(const f16_t* __restrict__ y,
        const float* __restrict__ ab, bf16_t* __restrict__ h, int total8) {
    __shared__ float a_s[128], b_s[128];
    int tid = threadIdx.x;
    if (tid < 128) { a_s[tid] = ab[tid]; b_s[tid] = ab[128 + tid]; }
    __syncthreads();
    for (int i = blockIdx.x * 256 + tid; i < total8; i += gridDim.x * 256) {
        f16x8 v = ((const f16x8*)y)[i];
        int c0 = (i * 8) & 127;
        bf16x8 o;
#pragma unroll
        for (int j = 0; j < 8; ++j)
            o[j] = (bf16_t)fmaxf(a_s[c0 + j] * (float)v[j] + b_s[c0 + j], 0.f);
        ((bf16x8*)h)[i] = o;
    }
}

// ---------------- W'^T: wpT[n][k] ----------------
__global__ __launch_bounds__(256) void k_wprime(const float* __restrict__ w_cn,
        bf16_t* __restrict__ wpT) {
    int k = blockIdx.x;
    int c = threadIdx.x & 127, half = threadIdx.x >> 7;
    if (half == 0)
        wpT[c * 128 + k] = (bf16_t)(w_cn[k * 128 + c] - w_cn[(128 + k) * 128 + c]);
    else
        wpT[(128 + c) * 128 + k] = (bf16_t)(w_cn[(128 + k) * 128 + c]);
}

// ---------------- k_uv: [u|v] = h @ W' -> group-major f16 [4][N][32] ----------------
__global__ __launch_bounds__(256) void k_uv(const bf16_t* __restrict__ h,
        const bf16_t* __restrict__ wpT, const float* __restrict__ b_cn,
        f16_t* __restrict__ u, f16_t* __restrict__ v, int N, int ntiles) {
    __shared__ bf16_t at[64 * 136];
    __shared__ f16_t ot[64 * 264];

    const int tid = threadIdx.x;
    const int lane = tid & 63;
    const int wv = tid >> 6;
    const int n0 = wv * 64;
    const int l16 = lane & 15;
    const int lg = lane >> 4;

    bf16x8 bfr[4][4];
#pragma unroll
    for (int s = 0; s < 4; ++s)
#pragma unroll
        for (int c = 0; c < 4; ++c)
            bfr[s][c] = *(const bf16x8*)(wpT + (n0 + 16 * c + l16) * 128 + 32 * s + 8 * lg);

    float bias[4];
#pragma unroll
    for (int c = 0; c < 4; ++c) {
        int n = n0 + 16 * c + l16;
        bias[c] = (n < 128) ? b_cn[n] : 0.f;
    }

    const int sr = tid >> 2, sq = tid & 3;

    for (int tile = blockIdx.x; tile < ntiles; tile += gridDim.x) {
        const int row0 = tile * 64;
        {
            int rg = row0 + sr; if (rg >= N) rg = N - 1;
            const bf16_t* hr = h + (size_t)rg * 128 + sq * 32;
            bf16_t* dr = at + sr * 136 + sq * 32;
#pragma unroll
            for (int c4 = 0; c4 < 4; ++c4)
                *(bf16x8*)(dr + c4 * 8) = *(const bf16x8*)(hr + c4 * 8);
        }
        __syncthreads();

        f32x4 acc[4][4];
#pragma unroll
        for (int c = 0; c < 4; ++c) {
            f32x4 ini = {bias[c], bias[c], bias[c], bias[c]};
#pragma unroll
            for (int rt = 0; rt < 4; ++rt) acc[rt][c] = ini;
        }
#pragma unroll
        for (int s = 0; s < 4; ++s) {
            bf16x8 afr[4];
#pragma unroll
            for (int rt = 0; rt < 4; ++rt)
                afr[rt] = *(const bf16x8*)(at + (rt * 16 + l16) * 136 + 32 * s + 8 * lg);
#pragma unroll
            for (int rt = 0; rt < 4; ++rt)
#pragma unroll
                for (int c = 0; c < 4; ++c)
                    acc[rt][c] = __builtin_amdgcn_mfma_f32_16x16x32_bf16(afr[rt], bfr[s][c], acc[rt][c], 0, 0, 0);
        }

#pragma unroll
        for (int rt = 0; rt < 4; ++rt)
#pragma unroll
            for (int c = 0; c < 4; ++c) {
                int n = n0 + 16 * c + l16;
#pragma unroll
                for (int reg = 0; reg < 4; ++reg) {
                    int r = rt * 16 + lg * 4 + reg;
                    ot[r * 264 + n] = (f16_t)acc[rt][c][reg];
                }
            }
        __syncthreads();

#pragma unroll
        for (int it = 0; it < 8; ++it) {
            int r = wv * 16 + it * 2 + (lane >> 5);
            int cc = (lane & 31) * 8;
            int rg = row0 + r;
            if (rg < N) {
                f16x8 w8 = *(const f16x8*)(ot + r * 264 + cc);
                if (cc < 128) {
                    int cg = cc >> 5, col = cc & 31;
                    *(f16x8*)(u + ((size_t)cg * N + rg) * 32 + col) = w8;
                } else {
                    int cv = cc - 128;
                    int cg = cv >> 5, col = cv & 31;
                    *(f16x8*)(v + ((size_t)cg * N + rg) * 32 + col) = w8;
                }
            }
        }
    }
}

// ---------------- counting sort of edges by g = seg[src[e]] ----------------
__global__ __launch_bounds__(256) void k_hist(const int* __restrict__ src,
        const int* __restrict__ seg, int* __restrict__ gcnt, int E) {
    __shared__ int lh[512];
    int tid = threadIdx.x;
    for (int i = tid; i < 512; i += 256) lh[i] = 0;
    __syncthreads();
    for (int e = blockIdx.x * 256 + tid; e < E; e += gridDim.x * 256)
        atomicAdd(&lh[seg[src[e]]], 1);
    __syncthreads();
    for (int i = tid; i < 512; i += 256)
        if (lh[i]) atomicAdd(&gcnt[i], lh[i]);
}

__global__ __launch_bounds__(512) void k_scan(const int* __restrict__ gcnt,
        int* __restrict__ offs, int* __restrict__ cursor) {
    __shared__ int s[512];
    int tid = threadIdx.x;
    s[tid] = gcnt[tid];
    __syncthreads();
    for (int off = 1; off < 512; off <<= 1) {
        int v = (tid >= off) ? s[tid - off] : 0;
        __syncthreads();
        s[tid] += v;
        __syncthreads();
    }
    offs[tid + 1] = s[tid];
    int ex = tid ? s[tid - 1] : 0;
    if (tid == 0) offs[0] = 0;
    cursor[tid] = ex;
}

// ---------------- k_scatter: one pass over src/dst/seg, LDS-cached; u32-packed output ----------------
// Requires N < 65536 (N=50000 here) so (si,di) pack into 32 bits.
__global__ __launch_bounds__(512) void k_scatter(const int* __restrict__ src,
        const int* __restrict__ dst, const int* __restrict__ seg,
        int* __restrict__ cursor, unsigned int* __restrict__ sorted, int E, int CH) {
    __shared__ int lh[512];
    __shared__ int lbase[512];
    __shared__ unsigned int pcache[SC_CAP];
    __shared__ unsigned short gcache[SC_CAP];
    const int tid = threadIdx.x;
    const int e0 = blockIdx.x * CH;
    const int e1 = min(E, e0 + CH);
    lh[tid] = 0;
    __syncthreads();
    for (int e = e0 + tid; e < e1; e += 512) {
        int si = src[e], di = dst[e];
        int g = seg[si];
        pcache[e - e0] = ((unsigned)si << 16) | (unsigned)di;
        gcache[e - e0] = (unsigned short)g;
        atomicAdd(&lh[g], 1);
    }
    __syncthreads();
    {
        int c = lh[tid];
        lbase[tid] = c ? atomicAdd(&cursor[tid], c) : 0;
        lh[tid] = 0;
    }
    __syncthreads();
    for (int e = e0 + tid; e < e1; e += 512) {
        int g = gcache[e - e0];
        int k = atomicAdd(&lh[g], 1);
        sorted[lbase[g] + k] = pcache[e - e0];
    }
}

// ---------------- k_agg_cg: one 32-col group per launch; XCD-swizzled graph chunks ----------------
// Grid 4G. If G%8==0: xcd = bid&7 owns graphs [xcd*G/8, (xcd+1)*G/8) (heuristic bid%8 -> XCD),
// so u-rows + edge list of a graph are fetched by ONE XCD's L2 only.
__global__ __launch_bounds__(256) void k_agg_cg(const unsigned int* __restrict__ sorted,
        const int* __restrict__ offs, const f16_t* __restrict__ u,
        const f16_t* __restrict__ v, float* __restrict__ p, int N, int G, int cg) {
    const int bid = blockIdx.x;
    int g, sp;
    if ((G & 7) == 0) {
        int gpx = G >> 3;
        int xcd = bid & 7, li = bid >> 3;
        g = xcd * gpx + (li >> 2);
        sp = li & 3;
    } else {
        g = bid >> 2; sp = bid & 3;
    }
    const int s0 = offs[g], s1 = offs[g + 1];
    const int tid = threadIdx.x;
    const int lane = tid & 63;
    const int wv = tid >> 6;
    const int sub = lane >> 2;          // 16 edges per wave
    const int c0 = (lane & 3) * 8;      // 8 cols per lane
    const f16_t* ug = u + (size_t)cg * N * 32;
    const f16_t* vg = v + (size_t)cg * N * 32;
    float acc[8] = {};
    // 2-deep unrolled edge loop for memory-level parallelism
    for (int base = s0 + (sp * 4 + wv) * 16; base < s1; base += 512) {
        int eA = base + sub;
        int eB = base + 256 + sub;
        bool okA = eA < s1, okB = eB < s1;
        unsigned pA = okA ? sorted[eA] : 0u;
        unsigned pB = okB ? sorted[eB] : 0u;
        f16x8 uuA = {}, vvA = {}, uuB = {}, vvB = {};
        if (okA) {
            uuA = *(const f16x8*)(ug + (size_t)(pA >> 16) * 32 + c0);
            vvA = *(const f16x8*)(vg + (size_t)(pA & 0xffffu) * 32 + c0);
        }
        if (okB) {
            uuB = *(const f16x8*)(ug + (size_t)(pB >> 16) * 32 + c0);
            vvB = *(const f16x8*)(vg + (size_t)(pB & 0xffffu) * 32 + c0);
        }
        if (okA) {
#pragma unroll
            for (int j = 0; j < 8; ++j)
                acc[j] += fmaxf((float)uuA[j] + (float)vvA[j], 0.f);
        }
        if (okB) {
#pragma unroll
            for (int j = 0; j < 8; ++j)
                acc[j] += fmaxf((float)uuB[j] + (float)vvB[j], 0.f);
        }
    }
#pragma unroll
    for (int j = 0; j < 8; ++j) {
        acc[j] += __shfl_xor(acc[j], 4, 64);
        acc[j] += __shfl_xor(acc[j], 8, 64);
        acc[j] += __shfl_xor(acc[j], 16, 64);
        acc[j] += __shfl_xor(acc[j], 32, 64);
    }
    __shared__ float red[4][4][8];
    if (lane < 4) {
#pragma unroll
        for (int j = 0; j < 8; ++j) red[wv][lane][j] = acc[j];
    }
    __syncthreads();
    if (tid < 32) {
        int cs = tid >> 3, j = tid & 7;
        float s = red[0][cs][j] + red[1][cs][j] + red[2][cs][j] + red[3][cs][j];
        atomicAdd(&p[g * 128 + cg * 32 + cs * 8 + j], s);
    }
}

// ---------------- Phase C: post MLP + BN + head ----------------
__global__ __launch_bounds__(256) void k_post_gemm(const float* __restrict__ p,
        const float* __restrict__ w_post, const float* __restrict__ b_post,
        float* __restrict__ y, float* __restrict__ stats) {
    int tid = threadIdx.x;
    int row0 = blockIdx.x * 16;
    int col = tid & 127, rg = tid >> 7;
    float acc[8] = {};
    for (int k = 0; k < 128; ++k) {
        float wv = w_post[k * 128 + col];
#pragma unroll
        for (int i = 0; i < 8; ++i) acc[i] += p[(row0 + rg * 8 + i) * 128 + k] * wv;
    }
    float b = b_post[col], s1 = 0.f, s2 = 0.f;
#pragma unroll
    for (int i = 0; i < 8; ++i) {
        float yv = acc[i] + b;
        y[(row0 + rg * 8 + i) * 128 + col] = yv;
        s1 += yv; s2 += yv * yv;
    }
    atomicAdd(&stats[col], s1);
    atomicAdd(&stats[128 + col], s2);
}

__global__ void k_post_finalize(const float* __restrict__ stats, const float* __restrict__ g_post,
                                const float* __restrict__ be_post, float* __restrict__ ab, float invG) {
    int c = threadIdx.x;
    float mu = stats[c] * invG;
    float var = stats[128 + c] * invG - mu * mu;
    float a = g_post[c] * rsqrtf(var + 1e-3f);
    ab[c] = a;
    ab[128 + c] = be_post[c] - mu * a;
}

__global__ __launch_bounds__(256) void k_out(const float* __restrict__ y,
        const float* __restrict__ ab, const float* __restrict__ w_out,
        const float* __restrict__ b_out, float* __restrict__ out) {
    int lane = threadIdx.x & 63;
    int wv = threadIdx.x >> 6;
    int row = blockIdx.x * 4 + wv;
    int c0 = lane * 2;
    float v = 0.f;
#pragma unroll
    for (int j = 0; j < 2; ++j) {
        int c = c0 + j;
        float t = fmaxf(ab[c] * y[row * 128 + c] + ab[128 + c], 0.f);
        v += t * w_out[c];
    }
#pragma unroll
    for (int m = 32; m >= 1; m >>= 1) v += __shfl_xor(v, m, 64);
    if (lane == 0) out[row] = 1.f / (1.f + expf(-(v + b_out[0])));
}

extern "C" void kernel_launch(void* const* d_in, const int* in_sizes, int n_in,
                              void* d_out, int out_size, void* d_ws, size_t ws_size,
                              hipStream_t stream) {
    const float* x      = (const float*)d_in[0];
    const int*   src    = (const int*)d_in[1];
    const int*   dst    = (const int*)d_in[2];
    const int*   seg    = (const int*)d_in[3];
    const float* w_pre  = (const float*)d_in[4];
    const float* b_pre  = (const float*)d_in[5];
    const float* g_pre  = (const float*)d_in[6];
    const float* be_pre = (const float*)d_in[7];
    const float* w_cn   = (const float*)d_in[8];
    const float* b_cn   = (const float*)d_in[9];
    const float* w_post = (const float*)d_in[10];
    const float* b_post = (const float*)d_in[11];
    const float* g_post = (const float*)d_in[12];
    const float* be_post= (const float*)d_in[13];
    const float* w_out  = (const float*)d_in[14];
    const float* b_out  = (const float*)d_in[15];
    const int E = in_sizes[1];
    const int N = in_sizes[3];
    const int G = out_size;

    char* ws = (char*)d_ws;
    float* stats_pre  = (float*)(ws + 0);        // zeroed each call
    float* stats_post = (float*)(ws + 1024);     // zeroed each call
    int*   gcnt       = (int*)(ws + 2048);       // zeroed each call
    float* ab_pre     = (float*)(ws + 4096);
    float* ab_post    = (float*)(ws + 5120);
    int*   offs       = (int*)(ws + 6144);
    int*   cursor     = (int*)(ws + 10240);
    bf16_t* wpT       = (bf16_t*)(ws + 12288);   // 64KB
    float* pbuf       = (float*)(ws + 131072);   // 256KB, zeroed (atomic accum)
    float* ybuf       = (float*)(ws + 131072 + 262144);
    size_t big0 = 1 << 20;
    size_t NB = (((size_t)N * 128 * 2) + 4095) & ~(size_t)4095;
    f16_t* ubuf = (f16_t*)(ws + big0);            // [4][N][32] f16
    f16_t* vbuf = (f16_t*)(ws + big0 + NB);       // [4][N][32] f16
    bf16_t* hbuf = (bf16_t*)(ws + big0 + 2 * NB);
    unsigned int* sorted = (unsigned int*)(ws + big0 + 2 * NB); // aliases hbuf (h dead before scatter)
    f16_t* ypre  = (f16_t*)(ws + big0 + 3 * NB);
    (void)ws_size;

    (void)hipMemsetAsync(d_ws, 0, 131072 + 262144, stream);

    int nb64 = (N + 63) / 64;
    k_pre_gemm<<<nb64, 256, 0, stream>>>(x, w_pre, b_pre, ypre, stats_pre, N);
    k_pre_finalize<<<1, 128, 0, stream>>>(stats_pre, g_pre, be_pre, ab_pre, 1.f / (float)N);
    k_apply<<<1024, 256, 0, stream>>>(ypre, ab_pre, hbuf, N * 128 / 8);
    k_wprime<<<128, 256, 0, stream>>>(w_cn, wpT);
    k_uv<<<256, 256, 0, stream>>>(hbuf, wpT, b_cn, ubuf, vbuf, N, nb64);
    k_hist<<<512, 256, 0, stream>>>(src, seg, gcnt, E);
    k_scan<<<1, 512, 0, stream>>>(gcnt, offs, cursor);
    int nsc = (E + SC_CAP - 1) / SC_CAP;
    k_scatter<<<nsc, 512, 0, stream>>>(src, dst, seg, cursor, sorted, E, SC_CAP);
    for (int cg = 0; cg < 4; ++cg)
        k_agg_cg<<<4 * G, 256, 0, stream>>>(sorted, offs, ubuf, vbuf, pbuf, N, G, cg);
    k_post_gemm<<<G / 16, 256, 0, stream>>>(pbuf, w_post, b_post, ybuf, stats_post);
    k_post_finalize<<<1, 128, 0, stream>>>(stats_post, g_post, be_post, ab_post, 1.f / (float)G);
    k_out<<<G / 4, 256, 0, stream>>>(ybuf, ab_post, w_out, b_out, (float*)d_out);
}